// Round 10
// baseline (1446.978 us; speedup 1.0000x reference)
//
#include <hip/hip_runtime.h>
#include <hip/hip_fp16.h>

#define N_NODES 100000
#define N_EDGES 1600000
#define N_GRAPHS 512
#define F 128
#define N_CONVS 4
#define SCAN_NBLK ((N_NODES + 1023) / 1024)   // 98

// two-phase fill, 256 subwindows so phase-B scatter fits in LDS
#define SUBW 256
#define SUBW_NODES 391                         // ceil(100000/256)
#define SCAP 7040                              // per-subwindow staging cap (mean 6256 + 10 sigma)
#define ACHUNK 4096
#define BINA_BLOCKS ((N_EDGES + ACHUNK - 1) / ACHUNK)  // 391
#define EBUF 8192                              // LDS edge buffer (mean 6256 + 24 sigma)

// channel-blocked aggregation v2: node-per-lane, 8 cb x 391 blocks
#define AGGV2_BPC ((N_NODES + 255) / 256)      // 391 blocks per channel-block

// packed W2 row stride: 256 bf16 (hi/lo interleaved) padded to 264 = 132 dwords
#define W2_STRIDE 132
#define W2_LAYER (128 * W2_STRIDE)            // dwords per layer

typedef __attribute__((ext_vector_type(8))) short short8;   // 8 bf16 (4 VGPRs)
typedef __attribute__((ext_vector_type(4))) float f32x4;

union FragU { uint4 u; short8 v; };
union HU4 { uint4 u; __half2 h[4]; };

// split f into truncated-bf16 hi/lo, packed (hi in low16, lo in high16).
__device__ __forceinline__ unsigned int pack_hilo(float f) {
    unsigned int u = __float_as_uint(f);
    unsigned int hb = u & 0xFFFF0000u;
    float d = f - __uint_as_float(hb);
    unsigned int lb = __float_as_uint(d) >> 16;
    return (u >> 16) | (lb << 16);
}

// ---------------- CSR build ----------------

__global__ void dinv_kernel(const int* __restrict__ cnt, float* __restrict__ dinv) {
    int n = blockIdx.x * blockDim.x + threadIdx.x;
    if (n < N_NODES) dinv[n] = rsqrtf((float)cnt[n] + 2.0f);  // improved=True
}

__global__ void scan1_kernel(const int* __restrict__ cnt, int* __restrict__ excl,
                             int* __restrict__ blksum) {
    __shared__ int sums[256];
    int t = threadIdx.x;
    int base = blockIdx.x * 1024 + t * 4;
    int v0 = 0, v1 = 0, v2 = 0, v3 = 0;
    if (base + 0 < N_NODES) v0 = cnt[base + 0];
    if (base + 1 < N_NODES) v1 = cnt[base + 1];
    if (base + 2 < N_NODES) v2 = cnt[base + 2];
    if (base + 3 < N_NODES) v3 = cnt[base + 3];
    int s = v0 + v1 + v2 + v3;
    sums[t] = s;
    __syncthreads();
    for (int off = 1; off < 256; off <<= 1) {
        int y = (t >= off) ? sums[t - off] : 0;
        __syncthreads();
        sums[t] += y;
        __syncthreads();
    }
    int pre = sums[t] - s;
    if (base + 0 < N_NODES) excl[base + 0] = pre;
    if (base + 1 < N_NODES) excl[base + 1] = pre + v0;
    if (base + 2 < N_NODES) excl[base + 2] = pre + v0 + v1;
    if (base + 3 < N_NODES) excl[base + 3] = pre + v0 + v1 + v2;
    if (t == 255) blksum[blockIdx.x] = sums[255];
}

__global__ void scan2_kernel(int* __restrict__ blksum, int nblk) {
    __shared__ int sh[128];
    int t = threadIdx.x;
    int v = (t < nblk) ? blksum[t] : 0;
    sh[t] = v;
    __syncthreads();
    for (int off = 1; off < 128; off <<= 1) {
        int y = (t >= off) ? sh[t - off] : 0;
        __syncthreads();
        sh[t] += y;
        __syncthreads();
    }
    if (t < nblk) blksum[t] = sh[t] - v;
}

__global__ void scan3_kernel(int* __restrict__ rowptr, const int* __restrict__ blksum) {
    int t = threadIdx.x;
    int base = blockIdx.x * 1024 + t * 4;
    int off = blksum[blockIdx.x];
#pragma unroll
    for (int i = 0; i < 4; i++) {
        int idx = base + i;
        if (idx < N_NODES) rowptr[idx] += off;
    }
    if (blockIdx.x == 0 && t == 0) rowptr[N_NODES] = N_EDGES;
}

// ---------------- Two-phase CSR fill, LDS-ordered ----------------
// Measured lessons:
//  (1) gfx950 L2 does NOT merge temporally-scattered 8 B stores — every
//      global-scatter scheme paid ~6x write-back amplification. Scatter in
//      LDS, write out coalesced.
//  (2) gfx950 global atomics scattered over a small array are also ~64 B
//      write-back each. Count in LDS per subwindow instead (subcount).

__global__ __launch_bounds__(256) void binA_kernel(
        const int* __restrict__ src, const int* __restrict__ dst,
        int* __restrict__ cursor, int2* __restrict__ staging) {
    __shared__ int2 buf[ACHUNK];                 // 32 KB
    __shared__ int cnt_s[SUBW], off_s[SUBW], cur_s[SUBW], gb_s[SUBW], sh[SUBW];
    int t = threadIdx.x;
    cnt_s[t] = 0;
    __syncthreads();

    int base = blockIdx.x * ACHUNK;
    int n = N_EDGES - base;
    if (n > ACHUNK) n = ACHUNK;

    // pass 1: count bins
    for (int li = t; li < n; li += 256)
        atomicAdd(&cnt_s[dst[base + li] / SUBW_NODES], 1);
    __syncthreads();

    // exclusive scan over 256 bins
    int v = cnt_s[t];
    sh[t] = v;
    __syncthreads();
    for (int off = 1; off < SUBW; off <<= 1) {
        int y = (t >= off) ? sh[t - off] : 0;
        __syncthreads();
        sh[t] += y;
        __syncthreads();
    }
    int excl = sh[t] - v;
    off_s[t] = excl;
    cur_s[t] = excl;
    gb_s[t] = atomicAdd(&cursor[t], v);
    __syncthreads();

    // pass 2: re-read (L2-hot) and scatter into LDS bin-contiguous buffer
    for (int li = t; li < n; li += 256) {
        int e = base + li;
        int d = dst[e], s = src[e];
        int p = atomicAdd(&cur_s[d / SUBW_NODES], 1);
        buf[p] = make_int2(s, d);
    }
    __syncthreads();

    // flush: contiguous ~128 B runs per bin into per-subwindow staging
    for (int i = t; i < n; i += 256) {
        int2 e = buf[i];
        int w = e.y / SUBW_NODES;
        int idx = gb_s[w] + (i - off_s[w]);
        if (idx < SCAP) staging[(size_t)w * SCAP + idx] = e;
    }
}

__global__ __launch_bounds__(256) void subcount_kernel(
        const int2* __restrict__ staging, const int* __restrict__ cursor,
        int* __restrict__ cnt) {
    __shared__ int hist[SUBW_NODES];
    int b = blockIdx.x, t = threadIdx.x;
    int n0 = b * SUBW_NODES;
    int n1 = n0 + SUBW_NODES;
    if (n1 > N_NODES) n1 = N_NODES;
    int nn = n1 - n0;
    for (int i = t; i < nn; i += 256) hist[i] = 0;
    __syncthreads();
    int m = cursor[b];
    if (m > SCAP) m = SCAP;
    for (int i = t; i < m; i += 256) {
        int d = staging[(size_t)b * SCAP + i].y;
        atomicAdd(&hist[d - n0], 1);
    }
    __syncthreads();
    for (int i = t; i < nn; i += 256) cnt[n0 + i] = hist[i];
}

__global__ __launch_bounds__(512) void binB_kernel(
        const int2* __restrict__ staging, const int* __restrict__ cursor,
        const int* __restrict__ rowptr, const float* __restrict__ dinv,
        int2* __restrict__ edges) {
    __shared__ int rowl[SUBW_NODES + 1];
    __shared__ int lcur[SUBW_NODES];
    __shared__ int2 ebuf[EBUF];                  // 64 KB
    int b = blockIdx.x, t = threadIdx.x;
    int n0 = b * SUBW_NODES;
    int n1 = n0 + SUBW_NODES;
    if (n1 > N_NODES) n1 = N_NODES;
    int nn = n1 - n0;

    for (int i = t; i <= nn; i += 512) rowl[i] = rowptr[n0 + i];
    for (int i = t; i < nn; i += 512) lcur[i] = 0;
    __syncthreads();

    int gb = rowl[0];
    int total = rowl[nn] - gb;
    int m = cursor[b];
    if (m > SCAP) m = SCAP;

    for (int i = t; i < m; i += 512) {
        int2 e = staging[(size_t)b * SCAP + i];
        int s = e.x, d = e.y;
        float wt = dinv[s] * dinv[d];
        int dl = d - n0;
        int lpos = (rowl[dl] - gb) + atomicAdd(&lcur[dl], 1);
        if (lpos < EBUF) ebuf[lpos] = make_int2(s, __float_as_int(wt));
    }
    __syncthreads();

    // fully coalesced ordered write-out of this subwindow's CSR range
    for (int i = t; i < total; i += 512)
        if (i < EBUF) edges[gb + i] = ebuf[i];
}

// ---------------- W pre-pack: conv_w[L][k][n] -> W2g[L][n][132 dwords] ----------------

__global__ void wpack_kernel(const float* __restrict__ conv_w, unsigned int* __restrict__ W2g) {
    int idx = blockIdx.x * 256 + threadIdx.x;
    if (idx < N_CONVS * 16384) {
        int L = idx >> 14;
        int e = idx & 16383;
        int k = e >> 7;
        int n = e & 127;
        float f = conv_w[(size_t)L * 16384 + k * 128 + n];
        W2g[(size_t)L * W2_LAYER + n * W2_STRIDE + k] = pack_hilo(f);
    }
}

// ---------------- MFMA GEMM: H = X @ W via split-bf16, 32 rows/wave ------
// Output (and fp16 input) use the CHANNEL-BLOCKED layout
//   buf[(cb*N_NODES + node)*16 + (c&15)],  cb = c>>4
// so each XCD's aggregation gather touches only its own 3.2 MB channel block.

template<bool F16IN>
__global__ __launch_bounds__(256, 2) void gemm_mfma_t(const void* __restrict__ Xv,
                                                      const unsigned int* __restrict__ W2g,
                                                      __half* __restrict__ Hh) {
    __shared__ unsigned int wlds[128 * W2_STRIDE];   // 67584 B
    int t = threadIdx.x;

    {   // stage packed W (16896 dwords)
        const uint4* s4 = (const uint4*)W2g;
        uint4* d4 = (uint4*)wlds;
#pragma unroll
        for (int i = 0; i < 17; i++) {
            int idx = i * 256 + t;
            if (idx < (128 * W2_STRIDE) / 4) d4[idx] = s4[idx];
        }
    }
    __syncthreads();

    int w = t >> 6;
    int l = t & 63;
    int m = l & 15;        // A row within tile / B col / C col
    int q = l >> 4;        // quad: k-offset q*8, C row-offset q*4
    int r0 = blockIdx.x * 128 + w * 32 + m;
    int r1 = r0 + 16;
    int r0c = (r0 > N_NODES - 1) ? (N_NODES - 1) : r0;
    int r1c = (r1 > N_NODES - 1) ? (N_NODES - 1) : r1;

    uint4 a0[8], a1[8];
#pragma unroll
    for (int i = 0; i < 8; i++) {
        if constexpr (F16IN) {
            // blocked layout: channels 16i+4q..+3 = block i, local ch 4q..4q+3
            const uint2* X2 = (const uint2*)Xv;   // 4 halves per uint2
            uint2 hv = X2[((size_t)i * N_NODES + r0c) * 4 + q];
            float2 f0 = __half22float2(*(const __half2*)&hv.x);
            float2 f1 = __half22float2(*(const __half2*)&hv.y);
            a0[i].x = pack_hilo(f0.x); a0[i].y = pack_hilo(f0.y);
            a0[i].z = pack_hilo(f1.x); a0[i].w = pack_hilo(f1.y);
            uint2 gv = X2[((size_t)i * N_NODES + r1c) * 4 + q];
            float2 g0 = __half22float2(*(const __half2*)&gv.x);
            float2 g1 = __half22float2(*(const __half2*)&gv.y);
            a1[i].x = pack_hilo(g0.x); a1[i].y = pack_hilo(g0.y);
            a1[i].z = pack_hilo(g1.x); a1[i].w = pack_hilo(g1.y);
        } else {
            const float4* X4 = (const float4*)Xv;  // fp32 row-major input (layer 0)
            float4 xv = X4[(size_t)r0c * 32 + i * 4 + q];
            a0[i].x = pack_hilo(xv.x); a0[i].y = pack_hilo(xv.y);
            a0[i].z = pack_hilo(xv.z); a0[i].w = pack_hilo(xv.w);
            float4 yv = X4[(size_t)r1c * 32 + i * 4 + q];
            a1[i].x = pack_hilo(yv.x); a1[i].y = pack_hilo(yv.y);
            a1[i].z = pack_hilo(yv.z); a1[i].w = pack_hilo(yv.w);
        }
    }

    f32x4 acc0[8], acc1[8];
#pragma unroll
    for (int nb = 0; nb < 8; nb++) {
        acc0[nb] = (f32x4){0.f, 0.f, 0.f, 0.f};
        acc1[nb] = (f32x4){0.f, 0.f, 0.f, 0.f};
    }

#pragma unroll
    for (int nb = 0; nb < 8; nb++) {
        const unsigned int* wb = &wlds[(nb * 16 + m) * W2_STRIDE];
#pragma unroll
        for (int i = 0; i < 8; i++) {
            uint4 b = *(const uint4*)(wb + i * 16 + q * 4);
            FragU fa0, fa1, fb, fr;
            fa0.u = a0[i]; fa1.u = a1[i]; fb.u = b;
            acc0[nb] = __builtin_amdgcn_mfma_f32_16x16x32_bf16(fa0.v, fb.v, acc0[nb], 0, 0, 0);
            acc1[nb] = __builtin_amdgcn_mfma_f32_16x16x32_bf16(fa1.v, fb.v, acc1[nb], 0, 0, 0);
            fr.u.x = (b.x >> 16) | (b.x << 16);
            fr.u.y = (b.y >> 16) | (b.y << 16);
            fr.u.z = (b.z >> 16) | (b.z << 16);
            fr.u.w = (b.w >> 16) | (b.w << 16);
            acc0[nb] = __builtin_amdgcn_mfma_f32_16x16x32_bf16(fa0.v, fr.v, acc0[nb], 0, 0, 0);
            acc1[nb] = __builtin_amdgcn_mfma_f32_16x16x32_bf16(fa1.v, fr.v, acc1[nb], 0, 0, 0);
        }
    }

    // C/D: col = m, row = q*4 + r; write channel-blocked: block nb, local ch m
    int rbase = blockIdx.x * 128 + w * 32 + q * 4;
#pragma unroll
    for (int nb = 0; nb < 8; nb++) {
#pragma unroll
        for (int r = 0; r < 4; r++) {
            int row = rbase + r;
            if (row < N_NODES)
                Hh[((size_t)nb * N_NODES + row) * 16 + m] = __float2half(acc0[nb][r]);
            int row1 = row + 16;
            if (row1 < N_NODES)
                Hh[((size_t)nb * N_NODES + row1) * 16 + m] = __float2half(acc1[nb][r]);
        }
    }
}

// ---------------- Channel-blocked aggregation v2: node-per-lane ----------------
// R8's aggb proved the traffic thesis (FETCH 193->80 MB) but replicated the
// per-node shuffle-reduction 8x -> ~3.3x instruction count -> 157 us at 66%
// VALUBusy. v2 keeps cb = blockIdx&7 XCD pinning (3.2 MB hot set in L2) and
// assigns ONE NODE PER LANE: serial edge walk, 16-ch accumulator in 4 float4
// regs, NO cross-lane reduction, prologue/epilogue once. Stores coalesce
// (32 B/lane, 2 KB/wave). Divergence from Poisson(16) degree spread ~1.8x.

__global__ __launch_bounds__(256) void aggv2_kernel(const uint4* __restrict__ Hq,
                                                    const int* __restrict__ rowptr,
                                                    const int2* __restrict__ edges,
                                                    const float* __restrict__ dinv,
                                                    const float4* __restrict__ bias4,
                                                    uint4* __restrict__ Xo) {
    int cb = blockIdx.x & 7;
    int node = (blockIdx.x >> 3) * 256 + threadIdx.x;
    if (node >= N_NODES) return;
    size_t cbase = (size_t)cb * N_NODES;

    int lo = rowptr[node];
    int hi = rowptr[node + 1];

    float4 a0 = make_float4(0.f, 0.f, 0.f, 0.f);
    float4 a1 = make_float4(0.f, 0.f, 0.f, 0.f);
    float4 a2 = make_float4(0.f, 0.f, 0.f, 0.f);
    float4 a3 = make_float4(0.f, 0.f, 0.f, 0.f);

    for (int i = lo; i < hi; ++i) {
        int2 e = edges[i];
        float w = __int_as_float(e.y);
        HU4 x0, x1;
        x0.u = Hq[(cbase + e.x) * 2];
        x1.u = Hq[(cbase + e.x) * 2 + 1];
        float2 p0 = __half22float2(x0.h[0]);
        float2 p1 = __half22float2(x0.h[1]);
        float2 p2 = __half22float2(x0.h[2]);
        float2 p3 = __half22float2(x0.h[3]);
        float2 p4 = __half22float2(x1.h[0]);
        float2 p5 = __half22float2(x1.h[1]);
        float2 p6 = __half22float2(x1.h[2]);
        float2 p7 = __half22float2(x1.h[3]);
        a0.x = fmaf(w, p0.x, a0.x); a0.y = fmaf(w, p0.y, a0.y);
        a0.z = fmaf(w, p1.x, a0.z); a0.w = fmaf(w, p1.y, a0.w);
        a1.x = fmaf(w, p2.x, a1.x); a1.y = fmaf(w, p2.y, a1.y);
        a1.z = fmaf(w, p3.x, a1.z); a1.w = fmaf(w, p3.y, a1.w);
        a2.x = fmaf(w, p4.x, a2.x); a2.y = fmaf(w, p4.y, a2.y);
        a2.z = fmaf(w, p5.x, a2.z); a2.w = fmaf(w, p5.y, a2.w);
        a3.x = fmaf(w, p6.x, a3.x); a3.y = fmaf(w, p6.y, a3.y);
        a3.z = fmaf(w, p7.x, a3.z); a3.w = fmaf(w, p7.y, a3.w);
    }

    float dn = dinv[node];
    float sw = 2.0f * dn * dn;
    HU4 s0, s1;
    s0.u = Hq[(cbase + node) * 2];
    s1.u = Hq[(cbase + node) * 2 + 1];
    float2 q0 = __half22float2(s0.h[0]);
    float2 q1 = __half22float2(s0.h[1]);
    float2 q2 = __half22float2(s0.h[2]);
    float2 q3 = __half22float2(s0.h[3]);
    float2 q4 = __half22float2(s1.h[0]);
    float2 q5 = __half22float2(s1.h[1]);
    float2 q6 = __half22float2(s1.h[2]);
    float2 q7 = __half22float2(s1.h[3]);
    float4 b0 = bias4[cb * 4 + 0];
    float4 b1 = bias4[cb * 4 + 1];
    float4 b2 = bias4[cb * 4 + 2];
    float4 b3 = bias4[cb * 4 + 3];
    float4 r0, r1, r2, r3;
    r0.x = fmaxf(fmaf(sw, q0.x, a0.x) + b0.x, 0.f);
    r0.y = fmaxf(fmaf(sw, q0.y, a0.y) + b0.y, 0.f);
    r0.z = fmaxf(fmaf(sw, q1.x, a0.z) + b0.z, 0.f);
    r0.w = fmaxf(fmaf(sw, q1.y, a0.w) + b0.w, 0.f);
    r1.x = fmaxf(fmaf(sw, q2.x, a1.x) + b1.x, 0.f);
    r1.y = fmaxf(fmaf(sw, q2.y, a1.y) + b1.y, 0.f);
    r1.z = fmaxf(fmaf(sw, q3.x, a1.z) + b1.z, 0.f);
    r1.w = fmaxf(fmaf(sw, q3.y, a1.w) + b1.w, 0.f);
    r2.x = fmaxf(fmaf(sw, q4.x, a2.x) + b2.x, 0.f);
    r2.y = fmaxf(fmaf(sw, q4.y, a2.y) + b2.y, 0.f);
    r2.z = fmaxf(fmaf(sw, q5.x, a2.z) + b2.z, 0.f);
    r2.w = fmaxf(fmaf(sw, q5.y, a2.w) + b2.w, 0.f);
    r3.x = fmaxf(fmaf(sw, q6.x, a3.x) + b3.x, 0.f);
    r3.y = fmaxf(fmaf(sw, q6.y, a3.y) + b3.y, 0.f);
    r3.z = fmaxf(fmaf(sw, q7.x, a3.z) + b3.z, 0.f);
    r3.w = fmaxf(fmaf(sw, q7.y, a3.w) + b3.w, 0.f);

    HU4 o0, o1;
    o0.h[0] = __floats2half2_rn(r0.x, r0.y);
    o0.h[1] = __floats2half2_rn(r0.z, r0.w);
    o0.h[2] = __floats2half2_rn(r1.x, r1.y);
    o0.h[3] = __floats2half2_rn(r1.z, r1.w);
    o1.h[0] = __floats2half2_rn(r2.x, r2.y);
    o1.h[1] = __floats2half2_rn(r2.z, r2.w);
    o1.h[2] = __floats2half2_rn(r3.x, r3.y);
    o1.h[3] = __floats2half2_rn(r3.z, r3.w);
    Xo[(cbase + node) * 2]     = o0.u;
    Xo[(cbase + node) * 2 + 1] = o1.u;
}

// ---------------- Fused mean-pool + FC1(relu) + FC2 (fp16 blocked x) ----------------

__global__ __launch_bounds__(256) void pool_fc_kernel(const __half* __restrict__ x,
                                                      const int* __restrict__ batch,
                                                      const float* __restrict__ fc1w,
                                                      const float* __restrict__ fc1b,
                                                      const float* __restrict__ fc2w,
                                                      const float* __restrict__ fc2b,
                                                      float* __restrict__ out) {
    __shared__ float part[2][F];
    __shared__ float pooled[F];
    __shared__ int bnd[2];
    __shared__ float red[2];
    int g = blockIdx.x, t = threadIdx.x;
    int c = t & 127, hlf = t >> 7;

    if (t < 2) {
        int target = g + t;
        int lo = 0, hi = N_NODES;
        while (lo < hi) {
            int m = (lo + hi) >> 1;
            if (batch[m] < target) lo = m + 1;
            else hi = m;
        }
        bnd[t] = lo;
    }
    __syncthreads();
    int lo = bnd[0], hi = bnd[1];

    // channel-blocked: x[(cb*N + n)*16 + (c&15)]
    size_t cboff = ((size_t)(c >> 4) * N_NODES) * 16 + (c & 15);

    float s = 0.f;
    int n = lo + hlf;
    for (; n + 6 < hi; n += 8) {
        float v0 = __half2float(x[cboff + (size_t)n * 16]);
        float v1 = __half2float(x[cboff + (size_t)(n + 2) * 16]);
        float v2 = __half2float(x[cboff + (size_t)(n + 4) * 16]);
        float v3 = __half2float(x[cboff + (size_t)(n + 6) * 16]);
        s += (v0 + v1) + (v2 + v3);
    }
    for (; n < hi; n += 2) s += __half2float(x[cboff + (size_t)n * 16]);
    part[hlf][c] = s;
    __syncthreads();

    if (t < F) {
        float cntf = fmaxf((float)(hi - lo), 1.0f);
        pooled[c] = (part[0][c] + part[1][c]) / cntf;
    }
    __syncthreads();

    if (t < F) {
        float acc = fc1b[t];
#pragma unroll 4
        for (int k = 0; k < F; k++) acc = fmaf(pooled[k], fc1w[k * F + t], acc);
        acc = fmaxf(acc, 0.f);

        float p = acc * fc2w[t];
#pragma unroll
        for (int o = 32; o > 0; o >>= 1) p += __shfl_down(p, o, 64);
        if ((t & 63) == 0) red[t >> 6] = p;
    }
    __syncthreads();
    if (t == 0) out[g] = red[0] + red[1] + fc2b[0];
}

// ---------------- launch ----------------

extern "C" void kernel_launch(void* const* d_in, const int* in_sizes, int n_in,
                              void* d_out, int out_size, void* d_ws, size_t ws_size,
                              hipStream_t stream) {
    const float* x_in   = (const float*)d_in[0];
    const int*   eidx   = (const int*)d_in[1];
    const int*   batch  = (const int*)d_in[2];
    const float* conv_w = (const float*)d_in[4];
    const float* conv_b = (const float*)d_in[5];
    const float* fc1w   = (const float*)d_in[6];
    const float* fc1b   = (const float*)d_in[7];
    const float* fc2w   = (const float*)d_in[8];
    const float* fc2b   = (const float*)d_in[9];
    float* out = (float*)d_out;

    const int* src = eidx;
    const int* dst = eidx + N_EDGES;

    char* ws = (char*)d_ws;
    size_t off = 0;
    auto alloc = [&](size_t bytes) -> char* {
        char* p = ws + off;
        off += (bytes + 255) & ~(size_t)255;
        return p;
    };
    __half* bufA  = (__half*)alloc((size_t)N_NODES * F * 2);   // 25.6 MB fp16 blocked (agg out)
    __half* bufH  = (__half*)alloc((size_t)N_NODES * F * 2);   // 25.6 MB fp16 blocked (gemm out)
    float*  dinv  = (float*)alloc((size_t)N_NODES * 4);
    int*    cnt   = (int*)alloc((size_t)N_NODES * 4);
    int*    rowp  = (int*)alloc((size_t)(N_NODES + 1) * 4);
    int2*   edges = (int2*)alloc((size_t)N_EDGES * 8);         // 12.8 MB packed
    unsigned int* W2g = (unsigned int*)alloc((size_t)N_CONVS * W2_LAYER * 4);  // 264 KB
    int*    blks  = (int*)alloc(128 * 4);
    int*    cursor = (int*)alloc(SUBW * 4);
    int2*   staging = (int2*)alloc((size_t)SUBW * SCAP * 8);   // 14.4 MB
    (void)ws_size; (void)in_sizes; (void)n_in; (void)out_size;

    // --- bucket edges first (needs no counts), then LDS-histogram counting ---
    hipMemsetAsync(cursor, 0, SUBW * 4, stream);
    binA_kernel<<<BINA_BLOCKS, 256, 0, stream>>>(src, dst, cursor, staging);
    subcount_kernel<<<SUBW, 256, 0, stream>>>(staging, cursor, cnt);

    // --- CSR prep + W pre-pack ---
    dinv_kernel<<<(N_NODES + 255) / 256, 256, 0, stream>>>(cnt, dinv);
    scan1_kernel<<<SCAN_NBLK, 256, 0, stream>>>(cnt, rowp, blks);
    scan2_kernel<<<1, 128, 0, stream>>>(blks, SCAN_NBLK);
    scan3_kernel<<<SCAN_NBLK, 256, 0, stream>>>(rowp, blks);
    wpack_kernel<<<(N_CONVS * 16384 + 255) / 256, 256, 0, stream>>>(conv_w, W2g);

    // --- LDS-ordered coalesced CSR fill ---
    binB_kernel<<<SUBW, 512, 0, stream>>>(staging, cursor, rowp, dinv, edges);

    // --- 4 GCN layers: MFMA GEMM (blocked fp16 out) + channel-blocked agg v2 ---
    for (int L = 0; L < N_CONVS; L++) {
        if (L == 0)
            gemm_mfma_t<false><<<(N_NODES + 127) / 128, 256, 0, stream>>>(
                (const void*)x_in, W2g, bufH);
        else
            gemm_mfma_t<true><<<(N_NODES + 127) / 128, 256, 0, stream>>>(
                (const void*)bufA, W2g + (size_t)L * W2_LAYER, bufH);
        aggv2_kernel<<<AGGV2_BPC * 8, 256, 0, stream>>>(
            (const uint4*)bufH, rowp, edges, dinv,
            (const float4*)(conv_b + (size_t)L * F), (uint4*)bufA);
    }

    // --- mean-pool + FC head ---
    pool_fc_kernel<<<N_GRAPHS, 256, 0, stream>>>(bufA, batch, fc1w, fc1b, fc2w, fc2b, out);
}

// Round 11
// 658.872 us; speedup vs baseline: 2.1961x; 2.1961x over previous
//
#include <hip/hip_runtime.h>
#include <hip/hip_fp16.h>

#define N_NODES 100000
#define N_EDGES 1600000
#define N_GRAPHS 512
#define F 128
#define N_CONVS 4
#define SCAN_NBLK ((N_NODES + 1023) / 1024)   // 98

// two-phase fill, 256 subwindows so phase-B scatter fits in LDS
#define SUBW 256
#define SUBW_NODES 391                         // ceil(100000/256)
#define SCAP 7040                              // per-subwindow staging cap (mean 6256 + 10 sigma)
#define ACHUNK 4096
#define BINA_BLOCKS ((N_EDGES + ACHUNK - 1) / ACHUNK)  // 391
#define EBUF 8192                              // LDS edge buffer (mean 6256 + 24 sigma)

// channel-blocked aggregation v3: 8 nodes/wave x 4 slots x 2 half-lanes
// 32 nodes per 256-thread block; 100000 = 32*3125 exactly (no tail divergence)
#define AGGV3_BLOCKS ((N_NODES / 32) * 8)      // 25000

// packed W2 row stride: 256 bf16 (hi/lo interleaved) padded to 264 = 132 dwords
#define W2_STRIDE 132
#define W2_LAYER (128 * W2_STRIDE)            // dwords per layer

typedef __attribute__((ext_vector_type(8))) short short8;   // 8 bf16 (4 VGPRs)
typedef __attribute__((ext_vector_type(4))) float f32x4;

union FragU { uint4 u; short8 v; };
union HU4 { uint4 u; __half2 h[4]; };

// split f into truncated-bf16 hi/lo, packed (hi in low16, lo in high16).
__device__ __forceinline__ unsigned int pack_hilo(float f) {
    unsigned int u = __float_as_uint(f);
    unsigned int hb = u & 0xFFFF0000u;
    float d = f - __uint_as_float(hb);
    unsigned int lb = __float_as_uint(d) >> 16;
    return (u >> 16) | (lb << 16);
}

// ---------------- CSR build ----------------

__global__ void dinv_kernel(const int* __restrict__ cnt, float* __restrict__ dinv) {
    int n = blockIdx.x * blockDim.x + threadIdx.x;
    if (n < N_NODES) dinv[n] = rsqrtf((float)cnt[n] + 2.0f);  // improved=True
}

__global__ void scan1_kernel(const int* __restrict__ cnt, int* __restrict__ excl,
                             int* __restrict__ blksum) {
    __shared__ int sums[256];
    int t = threadIdx.x;
    int base = blockIdx.x * 1024 + t * 4;
    int v0 = 0, v1 = 0, v2 = 0, v3 = 0;
    if (base + 0 < N_NODES) v0 = cnt[base + 0];
    if (base + 1 < N_NODES) v1 = cnt[base + 1];
    if (base + 2 < N_NODES) v2 = cnt[base + 2];
    if (base + 3 < N_NODES) v3 = cnt[base + 3];
    int s = v0 + v1 + v2 + v3;
    sums[t] = s;
    __syncthreads();
    for (int off = 1; off < 256; off <<= 1) {
        int y = (t >= off) ? sums[t - off] : 0;
        __syncthreads();
        sums[t] += y;
        __syncthreads();
    }
    int pre = sums[t] - s;
    if (base + 0 < N_NODES) excl[base + 0] = pre;
    if (base + 1 < N_NODES) excl[base + 1] = pre + v0;
    if (base + 2 < N_NODES) excl[base + 2] = pre + v0 + v1;
    if (base + 3 < N_NODES) excl[base + 3] = pre + v0 + v1 + v2;
    if (t == 255) blksum[blockIdx.x] = sums[255];
}

__global__ void scan2_kernel(int* __restrict__ blksum, int nblk) {
    __shared__ int sh[128];
    int t = threadIdx.x;
    int v = (t < nblk) ? blksum[t] : 0;
    sh[t] = v;
    __syncthreads();
    for (int off = 1; off < 128; off <<= 1) {
        int y = (t >= off) ? sh[t - off] : 0;
        __syncthreads();
        sh[t] += y;
        __syncthreads();
    }
    if (t < nblk) blksum[t] = sh[t] - v;
}

__global__ void scan3_kernel(int* __restrict__ rowptr, const int* __restrict__ blksum) {
    int t = threadIdx.x;
    int base = blockIdx.x * 1024 + t * 4;
    int off = blksum[blockIdx.x];
#pragma unroll
    for (int i = 0; i < 4; i++) {
        int idx = base + i;
        if (idx < N_NODES) rowptr[idx] += off;
    }
    if (blockIdx.x == 0 && t == 0) rowptr[N_NODES] = N_EDGES;
}

// ---------------- Two-phase CSR fill, LDS-ordered ----------------
// Measured lessons:
//  (1) gfx950 L2 does NOT merge temporally-scattered 8 B stores — every
//      global-scatter scheme paid ~6x write-back amplification. Scatter in
//      LDS, write out coalesced.
//  (2) gfx950 global atomics scattered over a small array are also ~64 B
//      write-back each. Count in LDS per subwindow instead (subcount).

__global__ __launch_bounds__(256) void binA_kernel(
        const int* __restrict__ src, const int* __restrict__ dst,
        int* __restrict__ cursor, int2* __restrict__ staging) {
    __shared__ int2 buf[ACHUNK];                 // 32 KB
    __shared__ int cnt_s[SUBW], off_s[SUBW], cur_s[SUBW], gb_s[SUBW], sh[SUBW];
    int t = threadIdx.x;
    cnt_s[t] = 0;
    __syncthreads();

    int base = blockIdx.x * ACHUNK;
    int n = N_EDGES - base;
    if (n > ACHUNK) n = ACHUNK;

    // pass 1: count bins
    for (int li = t; li < n; li += 256)
        atomicAdd(&cnt_s[dst[base + li] / SUBW_NODES], 1);
    __syncthreads();

    // exclusive scan over 256 bins
    int v = cnt_s[t];
    sh[t] = v;
    __syncthreads();
    for (int off = 1; off < SUBW; off <<= 1) {
        int y = (t >= off) ? sh[t - off] : 0;
        __syncthreads();
        sh[t] += y;
        __syncthreads();
    }
    int excl = sh[t] - v;
    off_s[t] = excl;
    cur_s[t] = excl;
    gb_s[t] = atomicAdd(&cursor[t], v);
    __syncthreads();

    // pass 2: re-read (L2-hot) and scatter into LDS bin-contiguous buffer
    for (int li = t; li < n; li += 256) {
        int e = base + li;
        int d = dst[e], s = src[e];
        int p = atomicAdd(&cur_s[d / SUBW_NODES], 1);
        buf[p] = make_int2(s, d);
    }
    __syncthreads();

    // flush: contiguous ~128 B runs per bin into per-subwindow staging
    for (int i = t; i < n; i += 256) {
        int2 e = buf[i];
        int w = e.y / SUBW_NODES;
        int idx = gb_s[w] + (i - off_s[w]);
        if (idx < SCAP) staging[(size_t)w * SCAP + idx] = e;
    }
}

__global__ __launch_bounds__(256) void subcount_kernel(
        const int2* __restrict__ staging, const int* __restrict__ cursor,
        int* __restrict__ cnt) {
    __shared__ int hist[SUBW_NODES];
    int b = blockIdx.x, t = threadIdx.x;
    int n0 = b * SUBW_NODES;
    int n1 = n0 + SUBW_NODES;
    if (n1 > N_NODES) n1 = N_NODES;
    int nn = n1 - n0;
    for (int i = t; i < nn; i += 256) hist[i] = 0;
    __syncthreads();
    int m = cursor[b];
    if (m > SCAP) m = SCAP;
    for (int i = t; i < m; i += 256) {
        int d = staging[(size_t)b * SCAP + i].y;
        atomicAdd(&hist[d - n0], 1);
    }
    __syncthreads();
    for (int i = t; i < nn; i += 256) cnt[n0 + i] = hist[i];
}

__global__ __launch_bounds__(512) void binB_kernel(
        const int2* __restrict__ staging, const int* __restrict__ cursor,
        const int* __restrict__ rowptr, const float* __restrict__ dinv,
        int2* __restrict__ edges) {
    __shared__ int rowl[SUBW_NODES + 1];
    __shared__ int lcur[SUBW_NODES];
    __shared__ int2 ebuf[EBUF];                  // 64 KB
    int b = blockIdx.x, t = threadIdx.x;
    int n0 = b * SUBW_NODES;
    int n1 = n0 + SUBW_NODES;
    if (n1 > N_NODES) n1 = N_NODES;
    int nn = n1 - n0;

    for (int i = t; i <= nn; i += 512) rowl[i] = rowptr[n0 + i];
    for (int i = t; i < nn; i += 512) lcur[i] = 0;
    __syncthreads();

    int gb = rowl[0];
    int total = rowl[nn] - gb;
    int m = cursor[b];
    if (m > SCAP) m = SCAP;

    for (int i = t; i < m; i += 512) {
        int2 e = staging[(size_t)b * SCAP + i];
        int s = e.x, d = e.y;
        float wt = dinv[s] * dinv[d];
        int dl = d - n0;
        int lpos = (rowl[dl] - gb) + atomicAdd(&lcur[dl], 1);
        if (lpos < EBUF) ebuf[lpos] = make_int2(s, __float_as_int(wt));
    }
    __syncthreads();

    // fully coalesced ordered write-out of this subwindow's CSR range
    for (int i = t; i < total; i += 512)
        if (i < EBUF) edges[gb + i] = ebuf[i];
}

// ---------------- W pre-pack: conv_w[L][k][n] -> W2g[L][n][132 dwords] ----------------

__global__ void wpack_kernel(const float* __restrict__ conv_w, unsigned int* __restrict__ W2g) {
    int idx = blockIdx.x * 256 + threadIdx.x;
    if (idx < N_CONVS * 16384) {
        int L = idx >> 14;
        int e = idx & 16383;
        int k = e >> 7;
        int n = e & 127;
        float f = conv_w[(size_t)L * 16384 + k * 128 + n];
        W2g[(size_t)L * W2_LAYER + n * W2_STRIDE + k] = pack_hilo(f);
    }
}

// ---------------- MFMA GEMM: H = X @ W via split-bf16, 32 rows/wave ------
// Output (and fp16 input) use the CHANNEL-BLOCKED layout
//   buf[(cb*N_NODES + node)*16 + (c&15)],  cb = c>>4
// so each XCD's aggregation gather touches only its own 3.2 MB channel block.

template<bool F16IN>
__global__ __launch_bounds__(256, 2) void gemm_mfma_t(const void* __restrict__ Xv,
                                                      const unsigned int* __restrict__ W2g,
                                                      __half* __restrict__ Hh) {
    __shared__ unsigned int wlds[128 * W2_STRIDE];   // 67584 B
    int t = threadIdx.x;

    {   // stage packed W (16896 dwords)
        const uint4* s4 = (const uint4*)W2g;
        uint4* d4 = (uint4*)wlds;
#pragma unroll
        for (int i = 0; i < 17; i++) {
            int idx = i * 256 + t;
            if (idx < (128 * W2_STRIDE) / 4) d4[idx] = s4[idx];
        }
    }
    __syncthreads();

    int w = t >> 6;
    int l = t & 63;
    int m = l & 15;        // A row within tile / B col / C col
    int q = l >> 4;        // quad: k-offset q*8, C row-offset q*4
    int r0 = blockIdx.x * 128 + w * 32 + m;
    int r1 = r0 + 16;
    int r0c = (r0 > N_NODES - 1) ? (N_NODES - 1) : r0;
    int r1c = (r1 > N_NODES - 1) ? (N_NODES - 1) : r1;

    uint4 a0[8], a1[8];
#pragma unroll
    for (int i = 0; i < 8; i++) {
        if constexpr (F16IN) {
            // blocked layout: channels 16i+4q..+3 = block i, local ch 4q..4q+3
            const uint2* X2 = (const uint2*)Xv;   // 4 halves per uint2
            uint2 hv = X2[((size_t)i * N_NODES + r0c) * 4 + q];
            float2 f0 = __half22float2(*(const __half2*)&hv.x);
            float2 f1 = __half22float2(*(const __half2*)&hv.y);
            a0[i].x = pack_hilo(f0.x); a0[i].y = pack_hilo(f0.y);
            a0[i].z = pack_hilo(f1.x); a0[i].w = pack_hilo(f1.y);
            uint2 gv = X2[((size_t)i * N_NODES + r1c) * 4 + q];
            float2 g0 = __half22float2(*(const __half2*)&gv.x);
            float2 g1 = __half22float2(*(const __half2*)&gv.y);
            a1[i].x = pack_hilo(g0.x); a1[i].y = pack_hilo(g0.y);
            a1[i].z = pack_hilo(g1.x); a1[i].w = pack_hilo(g1.y);
        } else {
            const float4* X4 = (const float4*)Xv;  // fp32 row-major input (layer 0)
            float4 xv = X4[(size_t)r0c * 32 + i * 4 + q];
            a0[i].x = pack_hilo(xv.x); a0[i].y = pack_hilo(xv.y);
            a0[i].z = pack_hilo(xv.z); a0[i].w = pack_hilo(xv.w);
            float4 yv = X4[(size_t)r1c * 32 + i * 4 + q];
            a1[i].x = pack_hilo(yv.x); a1[i].y = pack_hilo(yv.y);
            a1[i].z = pack_hilo(yv.z); a1[i].w = pack_hilo(yv.w);
        }
    }

    f32x4 acc0[8], acc1[8];
#pragma unroll
    for (int nb = 0; nb < 8; nb++) {
        acc0[nb] = (f32x4){0.f, 0.f, 0.f, 0.f};
        acc1[nb] = (f32x4){0.f, 0.f, 0.f, 0.f};
    }

#pragma unroll
    for (int nb = 0; nb < 8; nb++) {
        const unsigned int* wb = &wlds[(nb * 16 + m) * W2_STRIDE];
#pragma unroll
        for (int i = 0; i < 8; i++) {
            uint4 b = *(const uint4*)(wb + i * 16 + q * 4);
            FragU fa0, fa1, fb, fr;
            fa0.u = a0[i]; fa1.u = a1[i]; fb.u = b;
            acc0[nb] = __builtin_amdgcn_mfma_f32_16x16x32_bf16(fa0.v, fb.v, acc0[nb], 0, 0, 0);
            acc1[nb] = __builtin_amdgcn_mfma_f32_16x16x32_bf16(fa1.v, fb.v, acc1[nb], 0, 0, 0);
            fr.u.x = (b.x >> 16) | (b.x << 16);
            fr.u.y = (b.y >> 16) | (b.y << 16);
            fr.u.z = (b.z >> 16) | (b.z << 16);
            fr.u.w = (b.w >> 16) | (b.w << 16);
            acc0[nb] = __builtin_amdgcn_mfma_f32_16x16x32_bf16(fa0.v, fr.v, acc0[nb], 0, 0, 0);
            acc1[nb] = __builtin_amdgcn_mfma_f32_16x16x32_bf16(fa1.v, fr.v, acc1[nb], 0, 0, 0);
        }
    }

    // C/D: col = m, row = q*4 + r; write channel-blocked: block nb, local ch m
    int rbase = blockIdx.x * 128 + w * 32 + q * 4;
#pragma unroll
    for (int nb = 0; nb < 8; nb++) {
#pragma unroll
        for (int r = 0; r < 4; r++) {
            int row = rbase + r;
            if (row < N_NODES)
                Hh[((size_t)nb * N_NODES + row) * 16 + m] = __float2half(acc0[nb][r]);
            int row1 = row + 16;
            if (row1 < N_NODES)
                Hh[((size_t)nb * N_NODES + row1) * 16 + m] = __float2half(acc1[nb][r]);
        }
    }
}

// ---------------- Channel-blocked aggregation v3 ----------------
// Three measured lessons combined:
//  - cb = blockIdx&7 XCD-pinning minimizes FETCH (80 MB proven in aggb);
//  - consecutive nodes per WAVE keep the edge stream contiguous (aggv2's
//    node-per-lane scattered it -> 1 GB FETCH);
//  - 8 nodes/wave x 4 slots x 2 half-lanes amortizes per-node overhead
//    (aggb's 2 nodes/wave + 4-level reduction was instruction-bound, 157 us).
// lane = nsub(3b)|slot(2b)|half(1b). Per edge: 2 lanes read 32 B contiguous.
// Reduction: 2 shfl_xor levels (4, 2). 100000 = 32*3125 -> no tail.

__global__ __launch_bounds__(256) void aggv3_kernel(const uint4* __restrict__ Hq,
                                                    const int* __restrict__ rowptr,
                                                    const int2* __restrict__ edges,
                                                    const float* __restrict__ dinv,
                                                    const float4* __restrict__ bias4,
                                                    uint4* __restrict__ Xo) {
    int cb = blockIdx.x & 7;
    int wv = threadIdx.x >> 6;
    int lane = threadIdx.x & 63;
    int nsub = lane >> 3;          // 0..7: node within wave
    int slot = (lane >> 1) & 3;    // 0..3: edge slot
    int half = lane & 1;           // which uint4 (8 of 16 channels)
    int node = ((blockIdx.x >> 3) * 4 + wv) * 8 + nsub;
    size_t cbase = (size_t)cb * N_NODES;

    int lo = rowptr[node];
    int hi = rowptr[node + 1];

    float4 aL = make_float4(0.f, 0.f, 0.f, 0.f);
    float4 aH = make_float4(0.f, 0.f, 0.f, 0.f);

    for (int i = lo + slot; i < hi; i += 4) {
        int2 e = edges[i];
        float w = __int_as_float(e.y);
        HU4 x; x.u = Hq[(cbase + e.x) * 2 + half];
        float2 p0 = __half22float2(x.h[0]);
        float2 p1 = __half22float2(x.h[1]);
        float2 p2 = __half22float2(x.h[2]);
        float2 p3 = __half22float2(x.h[3]);
        aL.x = fmaf(w, p0.x, aL.x); aL.y = fmaf(w, p0.y, aL.y);
        aL.z = fmaf(w, p1.x, aL.z); aL.w = fmaf(w, p1.y, aL.w);
        aH.x = fmaf(w, p2.x, aH.x); aH.y = fmaf(w, p2.y, aH.y);
        aH.z = fmaf(w, p3.x, aH.z); aH.w = fmaf(w, p3.y, aH.w);
    }

    // reduce over slot (lane bits 2,1); node (bits 5-3) and half (bit 0) fixed
#pragma unroll
    for (int d = 4; d >= 2; d >>= 1) {
        aL.x += __shfl_xor(aL.x, d, 64); aL.y += __shfl_xor(aL.y, d, 64);
        aL.z += __shfl_xor(aL.z, d, 64); aL.w += __shfl_xor(aL.w, d, 64);
        aH.x += __shfl_xor(aH.x, d, 64); aH.y += __shfl_xor(aH.y, d, 64);
        aH.z += __shfl_xor(aH.z, d, 64); aH.w += __shfl_xor(aH.w, d, 64);
    }

    if (slot == 0) {
        float dn = dinv[node];
        float sw = 2.0f * dn * dn;
        HU4 x; x.u = Hq[(cbase + node) * 2 + half];
        float2 p0 = __half22float2(x.h[0]);
        float2 p1 = __half22float2(x.h[1]);
        float2 p2 = __half22float2(x.h[2]);
        float2 p3 = __half22float2(x.h[3]);
        float4 bL = bias4[cb * 4 + half * 2];
        float4 bH = bias4[cb * 4 + half * 2 + 1];
        float4 rL, rH;
        rL.x = fmaxf(fmaf(sw, p0.x, aL.x) + bL.x, 0.f);
        rL.y = fmaxf(fmaf(sw, p0.y, aL.y) + bL.y, 0.f);
        rL.z = fmaxf(fmaf(sw, p1.x, aL.z) + bL.z, 0.f);
        rL.w = fmaxf(fmaf(sw, p1.y, aL.w) + bL.w, 0.f);
        rH.x = fmaxf(fmaf(sw, p2.x, aH.x) + bH.x, 0.f);
        rH.y = fmaxf(fmaf(sw, p2.y, aH.y) + bH.y, 0.f);
        rH.z = fmaxf(fmaf(sw, p3.x, aH.z) + bH.z, 0.f);
        rH.w = fmaxf(fmaf(sw, p3.y, aH.w) + bH.w, 0.f);
        HU4 o;
        o.h[0] = __floats2half2_rn(rL.x, rL.y);
        o.h[1] = __floats2half2_rn(rL.z, rL.w);
        o.h[2] = __floats2half2_rn(rH.x, rH.y);
        o.h[3] = __floats2half2_rn(rH.z, rH.w);
        Xo[(cbase + node) * 2 + half] = o.u;
    }
}

// ---------------- Fused mean-pool + FC1(relu) + FC2 (fp16 blocked x) ----------------

__global__ __launch_bounds__(256) void pool_fc_kernel(const __half* __restrict__ x,
                                                      const int* __restrict__ batch,
                                                      const float* __restrict__ fc1w,
                                                      const float* __restrict__ fc1b,
                                                      const float* __restrict__ fc2w,
                                                      const float* __restrict__ fc2b,
                                                      float* __restrict__ out) {
    __shared__ float part[2][F];
    __shared__ float pooled[F];
    __shared__ int bnd[2];
    __shared__ float red[2];
    int g = blockIdx.x, t = threadIdx.x;
    int c = t & 127, hlf = t >> 7;

    if (t < 2) {
        int target = g + t;
        int lo = 0, hi = N_NODES;
        while (lo < hi) {
            int m = (lo + hi) >> 1;
            if (batch[m] < target) lo = m + 1;
            else hi = m;
        }
        bnd[t] = lo;
    }
    __syncthreads();
    int lo = bnd[0], hi = bnd[1];

    // channel-blocked: x[(cb*N + n)*16 + (c&15)]
    size_t cboff = ((size_t)(c >> 4) * N_NODES) * 16 + (c & 15);

    float s = 0.f;
    int n = lo + hlf;
    for (; n + 6 < hi; n += 8) {
        float v0 = __half2float(x[cboff + (size_t)n * 16]);
        float v1 = __half2float(x[cboff + (size_t)(n + 2) * 16]);
        float v2 = __half2float(x[cboff + (size_t)(n + 4) * 16]);
        float v3 = __half2float(x[cboff + (size_t)(n + 6) * 16]);
        s += (v0 + v1) + (v2 + v3);
    }
    for (; n < hi; n += 2) s += __half2float(x[cboff + (size_t)n * 16]);
    part[hlf][c] = s;
    __syncthreads();

    if (t < F) {
        float cntf = fmaxf((float)(hi - lo), 1.0f);
        pooled[c] = (part[0][c] + part[1][c]) / cntf;
    }
    __syncthreads();

    if (t < F) {
        float acc = fc1b[t];
#pragma unroll 4
        for (int k = 0; k < F; k++) acc = fmaf(pooled[k], fc1w[k * F + t], acc);
        acc = fmaxf(acc, 0.f);

        float p = acc * fc2w[t];
#pragma unroll
        for (int o = 32; o > 0; o >>= 1) p += __shfl_down(p, o, 64);
        if ((t & 63) == 0) red[t >> 6] = p;
    }
    __syncthreads();
    if (t == 0) out[g] = red[0] + red[1] + fc2b[0];
}

// ---------------- launch ----------------

extern "C" void kernel_launch(void* const* d_in, const int* in_sizes, int n_in,
                              void* d_out, int out_size, void* d_ws, size_t ws_size,
                              hipStream_t stream) {
    const float* x_in   = (const float*)d_in[0];
    const int*   eidx   = (const int*)d_in[1];
    const int*   batch  = (const int*)d_in[2];
    const float* conv_w = (const float*)d_in[4];
    const float* conv_b = (const float*)d_in[5];
    const float* fc1w   = (const float*)d_in[6];
    const float* fc1b   = (const float*)d_in[7];
    const float* fc2w   = (const float*)d_in[8];
    const float* fc2b   = (const float*)d_in[9];
    float* out = (float*)d_out;

    const int* src = eidx;
    const int* dst = eidx + N_EDGES;

    char* ws = (char*)d_ws;
    size_t off = 0;
    auto alloc = [&](size_t bytes) -> char* {
        char* p = ws + off;
        off += (bytes + 255) & ~(size_t)255;
        return p;
    };
    __half* bufA  = (__half*)alloc((size_t)N_NODES * F * 2);   // 25.6 MB fp16 blocked (agg out)
    __half* bufH  = (__half*)alloc((size_t)N_NODES * F * 2);   // 25.6 MB fp16 blocked (gemm out)
    float*  dinv  = (float*)alloc((size_t)N_NODES * 4);
    int*    cnt   = (int*)alloc((size_t)N_NODES * 4);
    int*    rowp  = (int*)alloc((size_t)(N_NODES + 1) * 4);
    int2*   edges = (int2*)alloc((size_t)N_EDGES * 8);         // 12.8 MB packed
    unsigned int* W2g = (unsigned int*)alloc((size_t)N_CONVS * W2_LAYER * 4);  // 264 KB
    int*    blks  = (int*)alloc(128 * 4);
    int*    cursor = (int*)alloc(SUBW * 4);
    int2*   staging = (int2*)alloc((size_t)SUBW * SCAP * 8);   // 14.4 MB
    (void)ws_size; (void)in_sizes; (void)n_in; (void)out_size;

    // --- bucket edges first (needs no counts), then LDS-histogram counting ---
    hipMemsetAsync(cursor, 0, SUBW * 4, stream);
    binA_kernel<<<BINA_BLOCKS, 256, 0, stream>>>(src, dst, cursor, staging);
    subcount_kernel<<<SUBW, 256, 0, stream>>>(staging, cursor, cnt);

    // --- CSR prep + W pre-pack ---
    dinv_kernel<<<(N_NODES + 255) / 256, 256, 0, stream>>>(cnt, dinv);
    scan1_kernel<<<SCAN_NBLK, 256, 0, stream>>>(cnt, rowp, blks);
    scan2_kernel<<<1, 128, 0, stream>>>(blks, SCAN_NBLK);
    scan3_kernel<<<SCAN_NBLK, 256, 0, stream>>>(rowp, blks);
    wpack_kernel<<<(N_CONVS * 16384 + 255) / 256, 256, 0, stream>>>(conv_w, W2g);

    // --- LDS-ordered coalesced CSR fill ---
    binB_kernel<<<SUBW, 512, 0, stream>>>(staging, cursor, rowp, dinv, edges);

    // --- 4 GCN layers: MFMA GEMM (blocked fp16 out) + channel-blocked agg v3 ---
    for (int L = 0; L < N_CONVS; L++) {
        if (L == 0)
            gemm_mfma_t<false><<<(N_NODES + 127) / 128, 256, 0, stream>>>(
                (const void*)x_in, W2g, bufH);
        else
            gemm_mfma_t<true><<<(N_NODES + 127) / 128, 256, 0, stream>>>(
                (const void*)bufA, W2g + (size_t)L * W2_LAYER, bufH);
        aggv3_kernel<<<AGGV3_BLOCKS, 256, 0, stream>>>(
            (const uint4*)bufH, rowp, edges, dinv,
            (const float4*)(conv_b + (size_t)L * F), (uint4*)bufA);
    }

    // --- mean-pool + FC head ---
    pool_fc_kernel<<<N_GRAPHS, 256, 0, stream>>>(bufA, batch, fc1w, fc1b, fc2w, fc2b, out);
}

// Round 12
// 630.645 us; speedup vs baseline: 2.2944x; 1.0448x over previous
//
#include <hip/hip_runtime.h>
#include <hip/hip_fp16.h>

#define N_NODES 100000
#define N_EDGES 1600000
#define N_GRAPHS 512
#define F 128
#define N_CONVS 4
#define SCAN_NBLK ((N_NODES + 1023) / 1024)   // 98

// two-phase fill, 256 subwindows so phase-B scatter fits in LDS
#define SUBW 256
#define SUBW_NODES 391                         // ceil(100000/256)
#define SCAP 7040                              // per-subwindow staging cap (mean 6256 + 10 sigma)
#define ACHUNK 4096
#define BINA_BLOCKS ((N_EDGES + ACHUNK - 1) / ACHUNK)  // 391
#define EBUF 8192                              // LDS edge buffer (mean 6256 + 24 sigma)

// channel-blocked aggregation v4: 8 nodes/wave x 4 slots x 2 half-lanes
// 32 nodes per 256-thread block; 100000 = 32*3125 exactly (no tail divergence)
#define AGGV4_BLOCKS ((N_NODES / 32) * 8)      // 25000

// packed W2 row stride: 256 bf16 (hi/lo interleaved) padded to 264 = 132 dwords
#define W2_STRIDE 132
#define W2_LAYER (128 * W2_STRIDE)            // dwords per layer

typedef __attribute__((ext_vector_type(8))) short short8;   // 8 bf16 (4 VGPRs)
typedef __attribute__((ext_vector_type(4))) float f32x4;

union FragU { uint4 u; short8 v; };
union HU4 { uint4 u; __half2 h[4]; };

// split f into truncated-bf16 hi/lo, packed (hi in low16, lo in high16).
__device__ __forceinline__ unsigned int pack_hilo(float f) {
    unsigned int u = __float_as_uint(f);
    unsigned int hb = u & 0xFFFF0000u;
    float d = f - __uint_as_float(hb);
    unsigned int lb = __float_as_uint(d) >> 16;
    return (u >> 16) | (lb << 16);
}

// ---------------- CSR build ----------------

__global__ void dinv_kernel(const int* __restrict__ cnt, float* __restrict__ dinv) {
    int n = blockIdx.x * blockDim.x + threadIdx.x;
    if (n < N_NODES) dinv[n] = rsqrtf((float)cnt[n] + 2.0f);  // improved=True
}

__global__ void scan1_kernel(const int* __restrict__ cnt, int* __restrict__ excl,
                             int* __restrict__ blksum) {
    __shared__ int sums[256];
    int t = threadIdx.x;
    int base = blockIdx.x * 1024 + t * 4;
    int v0 = 0, v1 = 0, v2 = 0, v3 = 0;
    if (base + 0 < N_NODES) v0 = cnt[base + 0];
    if (base + 1 < N_NODES) v1 = cnt[base + 1];
    if (base + 2 < N_NODES) v2 = cnt[base + 2];
    if (base + 3 < N_NODES) v3 = cnt[base + 3];
    int s = v0 + v1 + v2 + v3;
    sums[t] = s;
    __syncthreads();
    for (int off = 1; off < 256; off <<= 1) {
        int y = (t >= off) ? sums[t - off] : 0;
        __syncthreads();
        sums[t] += y;
        __syncthreads();
    }
    int pre = sums[t] - s;
    if (base + 0 < N_NODES) excl[base + 0] = pre;
    if (base + 1 < N_NODES) excl[base + 1] = pre + v0;
    if (base + 2 < N_NODES) excl[base + 2] = pre + v0 + v1;
    if (base + 3 < N_NODES) excl[base + 3] = pre + v0 + v1 + v2;
    if (t == 255) blksum[blockIdx.x] = sums[255];
}

__global__ void scan2_kernel(int* __restrict__ blksum, int nblk) {
    __shared__ int sh[128];
    int t = threadIdx.x;
    int v = (t < nblk) ? blksum[t] : 0;
    sh[t] = v;
    __syncthreads();
    for (int off = 1; off < 128; off <<= 1) {
        int y = (t >= off) ? sh[t - off] : 0;
        __syncthreads();
        sh[t] += y;
        __syncthreads();
    }
    if (t < nblk) blksum[t] = sh[t] - v;
}

__global__ void scan3_kernel(int* __restrict__ rowptr, const int* __restrict__ blksum) {
    int t = threadIdx.x;
    int base = blockIdx.x * 1024 + t * 4;
    int off = blksum[blockIdx.x];
#pragma unroll
    for (int i = 0; i < 4; i++) {
        int idx = base + i;
        if (idx < N_NODES) rowptr[idx] += off;
    }
    if (blockIdx.x == 0 && t == 0) rowptr[N_NODES] = N_EDGES;
}

// ---------------- Two-phase CSR fill, LDS-ordered ----------------
// Measured lessons:
//  (1) gfx950 L2 does NOT merge temporally-scattered 8 B stores — every
//      global-scatter scheme paid ~6x write-back amplification. Scatter in
//      LDS, write out coalesced.
//  (2) gfx950 global atomics scattered over a small array are also ~64 B
//      write-back each. Count in LDS per subwindow instead (subcount).

__global__ __launch_bounds__(256) void binA_kernel(
        const int* __restrict__ src, const int* __restrict__ dst,
        int* __restrict__ cursor, int2* __restrict__ staging) {
    __shared__ int2 buf[ACHUNK];                 // 32 KB
    __shared__ int cnt_s[SUBW], off_s[SUBW], cur_s[SUBW], gb_s[SUBW], sh[SUBW];
    int t = threadIdx.x;
    cnt_s[t] = 0;
    __syncthreads();

    int base = blockIdx.x * ACHUNK;
    int n = N_EDGES - base;
    if (n > ACHUNK) n = ACHUNK;

    // pass 1: count bins
    for (int li = t; li < n; li += 256)
        atomicAdd(&cnt_s[dst[base + li] / SUBW_NODES], 1);
    __syncthreads();

    // exclusive scan over 256 bins
    int v = cnt_s[t];
    sh[t] = v;
    __syncthreads();
    for (int off = 1; off < SUBW; off <<= 1) {
        int y = (t >= off) ? sh[t - off] : 0;
        __syncthreads();
        sh[t] += y;
        __syncthreads();
    }
    int excl = sh[t] - v;
    off_s[t] = excl;
    cur_s[t] = excl;
    gb_s[t] = atomicAdd(&cursor[t], v);
    __syncthreads();

    // pass 2: re-read (L2-hot) and scatter into LDS bin-contiguous buffer
    for (int li = t; li < n; li += 256) {
        int e = base + li;
        int d = dst[e], s = src[e];
        int p = atomicAdd(&cur_s[d / SUBW_NODES], 1);
        buf[p] = make_int2(s, d);
    }
    __syncthreads();

    // flush: contiguous ~128 B runs per bin into per-subwindow staging
    for (int i = t; i < n; i += 256) {
        int2 e = buf[i];
        int w = e.y / SUBW_NODES;
        int idx = gb_s[w] + (i - off_s[w]);
        if (idx < SCAP) staging[(size_t)w * SCAP + idx] = e;
    }
}

__global__ __launch_bounds__(256) void subcount_kernel(
        const int2* __restrict__ staging, const int* __restrict__ cursor,
        int* __restrict__ cnt) {
    __shared__ int hist[SUBW_NODES];
    int b = blockIdx.x, t = threadIdx.x;
    int n0 = b * SUBW_NODES;
    int n1 = n0 + SUBW_NODES;
    if (n1 > N_NODES) n1 = N_NODES;
    int nn = n1 - n0;
    for (int i = t; i < nn; i += 256) hist[i] = 0;
    __syncthreads();
    int m = cursor[b];
    if (m > SCAP) m = SCAP;
    for (int i = t; i < m; i += 256) {
        int d = staging[(size_t)b * SCAP + i].y;
        atomicAdd(&hist[d - n0], 1);
    }
    __syncthreads();
    for (int i = t; i < nn; i += 256) cnt[n0 + i] = hist[i];
}

__global__ __launch_bounds__(512) void binB_kernel(
        const int2* __restrict__ staging, const int* __restrict__ cursor,
        const int* __restrict__ rowptr, const float* __restrict__ dinv,
        int2* __restrict__ edges) {
    __shared__ int rowl[SUBW_NODES + 1];
    __shared__ int lcur[SUBW_NODES];
    __shared__ int2 ebuf[EBUF];                  // 64 KB
    int b = blockIdx.x, t = threadIdx.x;
    int n0 = b * SUBW_NODES;
    int n1 = n0 + SUBW_NODES;
    if (n1 > N_NODES) n1 = N_NODES;
    int nn = n1 - n0;

    for (int i = t; i <= nn; i += 512) rowl[i] = rowptr[n0 + i];
    for (int i = t; i < nn; i += 512) lcur[i] = 0;
    __syncthreads();

    int gb = rowl[0];
    int total = rowl[nn] - gb;
    int m = cursor[b];
    if (m > SCAP) m = SCAP;

    for (int i = t; i < m; i += 512) {
        int2 e = staging[(size_t)b * SCAP + i];
        int s = e.x, d = e.y;
        float wt = dinv[s] * dinv[d];
        int dl = d - n0;
        int lpos = (rowl[dl] - gb) + atomicAdd(&lcur[dl], 1);
        if (lpos < EBUF) ebuf[lpos] = make_int2(s, __float_as_int(wt));
    }
    __syncthreads();

    // fully coalesced ordered write-out of this subwindow's CSR range
    for (int i = t; i < total; i += 512)
        if (i < EBUF) edges[gb + i] = ebuf[i];
}

// ---------------- W pre-pack: conv_w[L][k][n] -> W2g[L][n][132 dwords] ----------------

__global__ void wpack_kernel(const float* __restrict__ conv_w, unsigned int* __restrict__ W2g) {
    int idx = blockIdx.x * 256 + threadIdx.x;
    if (idx < N_CONVS * 16384) {
        int L = idx >> 14;
        int e = idx & 16383;
        int k = e >> 7;
        int n = e & 127;
        float f = conv_w[(size_t)L * 16384 + k * 128 + n];
        W2g[(size_t)L * W2_LAYER + n * W2_STRIDE + k] = pack_hilo(f);
    }
}

// ---------------- MFMA GEMM: H = X @ W via split-bf16, 32 rows/wave ------
// Output (and fp16 input) use the CHANNEL-BLOCKED layout
//   buf[(cb*N_NODES + node)*16 + (c&15)],  cb = c>>4
// so each XCD's aggregation gather touches only its own 3.2 MB channel block.

template<bool F16IN>
__global__ __launch_bounds__(256, 2) void gemm_mfma_t(const void* __restrict__ Xv,
                                                      const unsigned int* __restrict__ W2g,
                                                      __half* __restrict__ Hh) {
    __shared__ unsigned int wlds[128 * W2_STRIDE];   // 67584 B
    int t = threadIdx.x;

    {   // stage packed W (16896 dwords)
        const uint4* s4 = (const uint4*)W2g;
        uint4* d4 = (uint4*)wlds;
#pragma unroll
        for (int i = 0; i < 17; i++) {
            int idx = i * 256 + t;
            if (idx < (128 * W2_STRIDE) / 4) d4[idx] = s4[idx];
        }
    }
    __syncthreads();

    int w = t >> 6;
    int l = t & 63;
    int m = l & 15;        // A row within tile / B col / C col
    int q = l >> 4;        // quad: k-offset q*8, C row-offset q*4
    int r0 = blockIdx.x * 128 + w * 32 + m;
    int r1 = r0 + 16;
    int r0c = (r0 > N_NODES - 1) ? (N_NODES - 1) : r0;
    int r1c = (r1 > N_NODES - 1) ? (N_NODES - 1) : r1;

    uint4 a0[8], a1[8];
#pragma unroll
    for (int i = 0; i < 8; i++) {
        if constexpr (F16IN) {
            // blocked layout: channels 16i+4q..+3 = block i, local ch 4q..4q+3
            const uint2* X2 = (const uint2*)Xv;   // 4 halves per uint2
            uint2 hv = X2[((size_t)i * N_NODES + r0c) * 4 + q];
            float2 f0 = __half22float2(*(const __half2*)&hv.x);
            float2 f1 = __half22float2(*(const __half2*)&hv.y);
            a0[i].x = pack_hilo(f0.x); a0[i].y = pack_hilo(f0.y);
            a0[i].z = pack_hilo(f1.x); a0[i].w = pack_hilo(f1.y);
            uint2 gv = X2[((size_t)i * N_NODES + r1c) * 4 + q];
            float2 g0 = __half22float2(*(const __half2*)&gv.x);
            float2 g1 = __half22float2(*(const __half2*)&gv.y);
            a1[i].x = pack_hilo(g0.x); a1[i].y = pack_hilo(g0.y);
            a1[i].z = pack_hilo(g1.x); a1[i].w = pack_hilo(g1.y);
        } else {
            const float4* X4 = (const float4*)Xv;  // fp32 row-major input (layer 0)
            float4 xv = X4[(size_t)r0c * 32 + i * 4 + q];
            a0[i].x = pack_hilo(xv.x); a0[i].y = pack_hilo(xv.y);
            a0[i].z = pack_hilo(xv.z); a0[i].w = pack_hilo(xv.w);
            float4 yv = X4[(size_t)r1c * 32 + i * 4 + q];
            a1[i].x = pack_hilo(yv.x); a1[i].y = pack_hilo(yv.y);
            a1[i].z = pack_hilo(yv.z); a1[i].w = pack_hilo(yv.w);
        }
    }

    f32x4 acc0[8], acc1[8];
#pragma unroll
    for (int nb = 0; nb < 8; nb++) {
        acc0[nb] = (f32x4){0.f, 0.f, 0.f, 0.f};
        acc1[nb] = (f32x4){0.f, 0.f, 0.f, 0.f};
    }

#pragma unroll
    for (int nb = 0; nb < 8; nb++) {
        const unsigned int* wb = &wlds[(nb * 16 + m) * W2_STRIDE];
#pragma unroll
        for (int i = 0; i < 8; i++) {
            uint4 b = *(const uint4*)(wb + i * 16 + q * 4);
            FragU fa0, fa1, fb, fr;
            fa0.u = a0[i]; fa1.u = a1[i]; fb.u = b;
            acc0[nb] = __builtin_amdgcn_mfma_f32_16x16x32_bf16(fa0.v, fb.v, acc0[nb], 0, 0, 0);
            acc1[nb] = __builtin_amdgcn_mfma_f32_16x16x32_bf16(fa1.v, fb.v, acc1[nb], 0, 0, 0);
            fr.u.x = (b.x >> 16) | (b.x << 16);
            fr.u.y = (b.y >> 16) | (b.y << 16);
            fr.u.z = (b.z >> 16) | (b.z << 16);
            fr.u.w = (b.w >> 16) | (b.w << 16);
            acc0[nb] = __builtin_amdgcn_mfma_f32_16x16x32_bf16(fa0.v, fr.v, acc0[nb], 0, 0, 0);
            acc1[nb] = __builtin_amdgcn_mfma_f32_16x16x32_bf16(fa1.v, fr.v, acc1[nb], 0, 0, 0);
        }
    }

    // C/D: col = m, row = q*4 + r; write channel-blocked: block nb, local ch m
    int rbase = blockIdx.x * 128 + w * 32 + q * 4;
#pragma unroll
    for (int nb = 0; nb < 8; nb++) {
#pragma unroll
        for (int r = 0; r < 4; r++) {
            int row = rbase + r;
            if (row < N_NODES)
                Hh[((size_t)nb * N_NODES + row) * 16 + m] = __float2half(acc0[nb][r]);
            int row1 = row + 16;
            if (row1 < N_NODES)
                Hh[((size_t)nb * N_NODES + row1) * 16 + m] = __float2half(acc1[nb][r]);
        }
    }
}

// ---------------- Channel-blocked aggregation v4 ----------------
// aggv3 post-mortem: FETCH 116 MB as designed, but 99 us at 1.45 TB/s and
// 35% VALU -> LATENCY-bound. Its loop had one dependent edge->gather chain
// in flight per lane; R7's 62 us loop batched 4 edges (4 independent loads,
// then 4 independent gathers = 4x MLP). v4 = aggv3's lane mapping + cb
// pinning + R7's 4-batch: stride 16/node, clamp-to-him1 + zero-weight tail.

__global__ __launch_bounds__(256) void aggv4_kernel(const uint4* __restrict__ Hq,
                                                    const int* __restrict__ rowptr,
                                                    const int2* __restrict__ edges,
                                                    const float* __restrict__ dinv,
                                                    const float4* __restrict__ bias4,
                                                    uint4* __restrict__ Xo) {
    int cb = blockIdx.x & 7;
    int wv = threadIdx.x >> 6;
    int lane = threadIdx.x & 63;
    int nsub = lane >> 3;          // 0..7: node within wave
    int slot = (lane >> 1) & 3;    // 0..3: edge slot
    int half = lane & 1;           // which uint4 (8 of 16 channels)
    int node = ((blockIdx.x >> 3) * 4 + wv) * 8 + nsub;
    size_t cbase = (size_t)cb * N_NODES;

    int lo = rowptr[node];
    int hi = rowptr[node + 1];
    int him1 = hi - 1;

    float4 aL = make_float4(0.f, 0.f, 0.f, 0.f);
    float4 aH = make_float4(0.f, 0.f, 0.f, 0.f);

    for (int i = lo + slot; i < hi; i += 16) {
        int s[4]; float w[4]; uint4 v[4];
#pragma unroll
        for (int j = 0; j < 4; j++) {
            int ij = i + 4 * j;
            int cj = (ij < him1) ? ij : him1;
            int2 e = edges[cj];
            s[j] = e.x;
            w[j] = (ij < hi) ? __int_as_float(e.y) : 0.f;
        }
#pragma unroll
        for (int j = 0; j < 4; j++) v[j] = Hq[(cbase + s[j]) * 2 + half];
#pragma unroll
        for (int j = 0; j < 4; j++) {
            HU4 x; x.u = v[j];
            float2 p0 = __half22float2(x.h[0]);
            float2 p1 = __half22float2(x.h[1]);
            float2 p2 = __half22float2(x.h[2]);
            float2 p3 = __half22float2(x.h[3]);
            aL.x = fmaf(w[j], p0.x, aL.x); aL.y = fmaf(w[j], p0.y, aL.y);
            aL.z = fmaf(w[j], p1.x, aL.z); aL.w = fmaf(w[j], p1.y, aL.w);
            aH.x = fmaf(w[j], p2.x, aH.x); aH.y = fmaf(w[j], p2.y, aH.y);
            aH.z = fmaf(w[j], p3.x, aH.z); aH.w = fmaf(w[j], p3.y, aH.w);
        }
    }

    // reduce over slot (lane bits 2,1); node (bits 5-3) and half (bit 0) fixed
#pragma unroll
    for (int d = 4; d >= 2; d >>= 1) {
        aL.x += __shfl_xor(aL.x, d, 64); aL.y += __shfl_xor(aL.y, d, 64);
        aL.z += __shfl_xor(aL.z, d, 64); aL.w += __shfl_xor(aL.w, d, 64);
        aH.x += __shfl_xor(aH.x, d, 64); aH.y += __shfl_xor(aH.y, d, 64);
        aH.z += __shfl_xor(aH.z, d, 64); aH.w += __shfl_xor(aH.w, d, 64);
    }

    if (slot == 0) {
        float dn = dinv[node];
        float sw = 2.0f * dn * dn;
        HU4 x; x.u = Hq[(cbase + node) * 2 + half];
        float2 p0 = __half22float2(x.h[0]);
        float2 p1 = __half22float2(x.h[1]);
        float2 p2 = __half22float2(x.h[2]);
        float2 p3 = __half22float2(x.h[3]);
        float4 bL = bias4[cb * 4 + half * 2];
        float4 bH = bias4[cb * 4 + half * 2 + 1];
        float4 rL, rH;
        rL.x = fmaxf(fmaf(sw, p0.x, aL.x) + bL.x, 0.f);
        rL.y = fmaxf(fmaf(sw, p0.y, aL.y) + bL.y, 0.f);
        rL.z = fmaxf(fmaf(sw, p1.x, aL.z) + bL.z, 0.f);
        rL.w = fmaxf(fmaf(sw, p1.y, aL.w) + bL.w, 0.f);
        rH.x = fmaxf(fmaf(sw, p2.x, aH.x) + bH.x, 0.f);
        rH.y = fmaxf(fmaf(sw, p2.y, aH.y) + bH.y, 0.f);
        rH.z = fmaxf(fmaf(sw, p3.x, aH.z) + bH.z, 0.f);
        rH.w = fmaxf(fmaf(sw, p3.y, aH.w) + bH.w, 0.f);
        HU4 o;
        o.h[0] = __floats2half2_rn(rL.x, rL.y);
        o.h[1] = __floats2half2_rn(rL.z, rL.w);
        o.h[2] = __floats2half2_rn(rH.x, rH.y);
        o.h[3] = __floats2half2_rn(rH.z, rH.w);
        Xo[(cbase + node) * 2 + half] = o.u;
    }
}

// ---------------- Fused mean-pool + FC1(relu) + FC2 (fp16 blocked x) ----------------

__global__ __launch_bounds__(256) void pool_fc_kernel(const __half* __restrict__ x,
                                                      const int* __restrict__ batch,
                                                      const float* __restrict__ fc1w,
                                                      const float* __restrict__ fc1b,
                                                      const float* __restrict__ fc2w,
                                                      const float* __restrict__ fc2b,
                                                      float* __restrict__ out) {
    __shared__ float part[2][F];
    __shared__ float pooled[F];
    __shared__ int bnd[2];
    __shared__ float red[2];
    int g = blockIdx.x, t = threadIdx.x;
    int c = t & 127, hlf = t >> 7;

    if (t < 2) {
        int target = g + t;
        int lo = 0, hi = N_NODES;
        while (lo < hi) {
            int m = (lo + hi) >> 1;
            if (batch[m] < target) lo = m + 1;
            else hi = m;
        }
        bnd[t] = lo;
    }
    __syncthreads();
    int lo = bnd[0], hi = bnd[1];

    // channel-blocked: x[(cb*N + n)*16 + (c&15)]
    size_t cboff = ((size_t)(c >> 4) * N_NODES) * 16 + (c & 15);

    float s = 0.f;
    int n = lo + hlf;
    for (; n + 6 < hi; n += 8) {
        float v0 = __half2float(x[cboff + (size_t)n * 16]);
        float v1 = __half2float(x[cboff + (size_t)(n + 2) * 16]);
        float v2 = __half2float(x[cboff + (size_t)(n + 4) * 16]);
        float v3 = __half2float(x[cboff + (size_t)(n + 6) * 16]);
        s += (v0 + v1) + (v2 + v3);
    }
    for (; n < hi; n += 2) s += __half2float(x[cboff + (size_t)n * 16]);
    part[hlf][c] = s;
    __syncthreads();

    if (t < F) {
        float cntf = fmaxf((float)(hi - lo), 1.0f);
        pooled[c] = (part[0][c] + part[1][c]) / cntf;
    }
    __syncthreads();

    if (t < F) {
        float acc = fc1b[t];
#pragma unroll 4
        for (int k = 0; k < F; k++) acc = fmaf(pooled[k], fc1w[k * F + t], acc);
        acc = fmaxf(acc, 0.f);

        float p = acc * fc2w[t];
#pragma unroll
        for (int o = 32; o > 0; o >>= 1) p += __shfl_down(p, o, 64);
        if ((t & 63) == 0) red[t >> 6] = p;
    }
    __syncthreads();
    if (t == 0) out[g] = red[0] + red[1] + fc2b[0];
}

// ---------------- launch ----------------

extern "C" void kernel_launch(void* const* d_in, const int* in_sizes, int n_in,
                              void* d_out, int out_size, void* d_ws, size_t ws_size,
                              hipStream_t stream) {
    const float* x_in   = (const float*)d_in[0];
    const int*   eidx   = (const int*)d_in[1];
    const int*   batch  = (const int*)d_in[2];
    const float* conv_w = (const float*)d_in[4];
    const float* conv_b = (const float*)d_in[5];
    const float* fc1w   = (const float*)d_in[6];
    const float* fc1b   = (const float*)d_in[7];
    const float* fc2w   = (const float*)d_in[8];
    const float* fc2b   = (const float*)d_in[9];
    float* out = (float*)d_out;

    const int* src = eidx;
    const int* dst = eidx + N_EDGES;

    char* ws = (char*)d_ws;
    size_t off = 0;
    auto alloc = [&](size_t bytes) -> char* {
        char* p = ws + off;
        off += (bytes + 255) & ~(size_t)255;
        return p;
    };
    __half* bufA  = (__half*)alloc((size_t)N_NODES * F * 2);   // 25.6 MB fp16 blocked (agg out)
    __half* bufH  = (__half*)alloc((size_t)N_NODES * F * 2);   // 25.6 MB fp16 blocked (gemm out)
    float*  dinv  = (float*)alloc((size_t)N_NODES * 4);
    int*    cnt   = (int*)alloc((size_t)N_NODES * 4);
    int*    rowp  = (int*)alloc((size_t)(N_NODES + 1) * 4);
    int2*   edges = (int2*)alloc((size_t)N_EDGES * 8);         // 12.8 MB packed
    unsigned int* W2g = (unsigned int*)alloc((size_t)N_CONVS * W2_LAYER * 4);  // 264 KB
    int*    blks  = (int*)alloc(128 * 4);
    int*    cursor = (int*)alloc(SUBW * 4);
    int2*   staging = (int2*)alloc((size_t)SUBW * SCAP * 8);   // 14.4 MB
    (void)ws_size; (void)in_sizes; (void)n_in; (void)out_size;

    // --- bucket edges first (needs no counts), then LDS-histogram counting ---
    hipMemsetAsync(cursor, 0, SUBW * 4, stream);
    binA_kernel<<<BINA_BLOCKS, 256, 0, stream>>>(src, dst, cursor, staging);
    subcount_kernel<<<SUBW, 256, 0, stream>>>(staging, cursor, cnt);

    // --- CSR prep + W pre-pack ---
    dinv_kernel<<<(N_NODES + 255) / 256, 256, 0, stream>>>(cnt, dinv);
    scan1_kernel<<<SCAN_NBLK, 256, 0, stream>>>(cnt, rowp, blks);
    scan2_kernel<<<1, 128, 0, stream>>>(blks, SCAN_NBLK);
    scan3_kernel<<<SCAN_NBLK, 256, 0, stream>>>(rowp, blks);
    wpack_kernel<<<(N_CONVS * 16384 + 255) / 256, 256, 0, stream>>>(conv_w, W2g);

    // --- LDS-ordered coalesced CSR fill ---
    binB_kernel<<<SUBW, 512, 0, stream>>>(staging, cursor, rowp, dinv, edges);

    // --- 4 GCN layers: MFMA GEMM (blocked fp16 out) + channel-blocked agg v4 ---
    for (int L = 0; L < N_CONVS; L++) {
        if (L == 0)
            gemm_mfma_t<false><<<(N_NODES + 127) / 128, 256, 0, stream>>>(
                (const void*)x_in, W2g, bufH);
        else
            gemm_mfma_t<true><<<(N_NODES + 127) / 128, 256, 0, stream>>>(
                (const void*)bufA, W2g + (size_t)L * W2_LAYER, bufH);
        aggv4_kernel<<<AGGV4_BLOCKS, 256, 0, stream>>>(
            (const uint4*)bufH, rowp, edges, dinv,
            (const float4*)(conv_b + (size_t)L * F), (uint4*)bufA);
    }

    // --- mean-pool + FC head ---
    pool_fc_kernel<<<N_GRAPHS, 256, 0, stream>>>(bufA, batch, fc1w, fc1b, fc2w, fc2b, out);
}

// Round 13
// 518.951 us; speedup vs baseline: 2.7883x; 1.2152x over previous
//
#include <hip/hip_runtime.h>
#include <hip/hip_fp16.h>

#define N_NODES 100000
#define N_EDGES 1600000
#define N_GRAPHS 512
#define F 128
#define N_CONVS 4
#define SCAN_NBLK ((N_NODES + 1023) / 1024)   // 98

// two-phase fill, 256 subwindows so phase-B scatter fits in LDS
#define SUBW 256
#define SUBW_NODES 391                         // ceil(100000/256)
#define SCAP 7040                              // per-subwindow staging cap (mean 6256 + 10 sigma)
#define ACHUNK 4096
#define BINA_BLOCKS ((N_EDGES + ACHUNK - 1) / ACHUNK)  // 391
#define EBUF 8192                              // LDS edge buffer (mean 6256 + 24 sigma)

// packed W2 row stride: 256 bf16 (hi/lo interleaved) padded to 264 = 132 dwords
#define W2_STRIDE 132
#define W2_LAYER (128 * W2_STRIDE)            // dwords per layer

typedef __attribute__((ext_vector_type(8))) short short8;   // 8 bf16 (4 VGPRs)
typedef __attribute__((ext_vector_type(4))) float f32x4;

union FragU { uint4 u; short8 v; };
union HU4 { uint4 u; __half2 h[4]; };

// split f into truncated-bf16 hi/lo, packed (hi in low16, lo in high16).
__device__ __forceinline__ unsigned int pack_hilo(float f) {
    unsigned int u = __float_as_uint(f);
    unsigned int hb = u & 0xFFFF0000u;
    float d = f - __uint_as_float(hb);
    unsigned int lb = __float_as_uint(d) >> 16;
    return (u >> 16) | (lb << 16);
}

// ---------------- CSR build ----------------

__global__ void dinv_kernel(const int* __restrict__ cnt, float* __restrict__ dinv) {
    int n = blockIdx.x * blockDim.x + threadIdx.x;
    if (n < N_NODES) dinv[n] = rsqrtf((float)cnt[n] + 2.0f);  // improved=True
}

__global__ void scan1_kernel(const int* __restrict__ cnt, int* __restrict__ excl,
                             int* __restrict__ blksum) {
    __shared__ int sums[256];
    int t = threadIdx.x;
    int base = blockIdx.x * 1024 + t * 4;
    int v0 = 0, v1 = 0, v2 = 0, v3 = 0;
    if (base + 0 < N_NODES) v0 = cnt[base + 0];
    if (base + 1 < N_NODES) v1 = cnt[base + 1];
    if (base + 2 < N_NODES) v2 = cnt[base + 2];
    if (base + 3 < N_NODES) v3 = cnt[base + 3];
    int s = v0 + v1 + v2 + v3;
    sums[t] = s;
    __syncthreads();
    for (int off = 1; off < 256; off <<= 1) {
        int y = (t >= off) ? sums[t - off] : 0;
        __syncthreads();
        sums[t] += y;
        __syncthreads();
    }
    int pre = sums[t] - s;
    if (base + 0 < N_NODES) excl[base + 0] = pre;
    if (base + 1 < N_NODES) excl[base + 1] = pre + v0;
    if (base + 2 < N_NODES) excl[base + 2] = pre + v0 + v1;
    if (base + 3 < N_NODES) excl[base + 3] = pre + v0 + v1 + v2;
    if (t == 255) blksum[blockIdx.x] = sums[255];
}

__global__ void scan2_kernel(int* __restrict__ blksum, int nblk) {
    __shared__ int sh[128];
    int t = threadIdx.x;
    int v = (t < nblk) ? blksum[t] : 0;
    sh[t] = v;
    __syncthreads();
    for (int off = 1; off < 128; off <<= 1) {
        int y = (t >= off) ? sh[t - off] : 0;
        __syncthreads();
        sh[t] += y;
        __syncthreads();
    }
    if (t < nblk) blksum[t] = sh[t] - v;
}

__global__ void scan3_kernel(int* __restrict__ rowptr, const int* __restrict__ blksum) {
    int t = threadIdx.x;
    int base = blockIdx.x * 1024 + t * 4;
    int off = blksum[blockIdx.x];
#pragma unroll
    for (int i = 0; i < 4; i++) {
        int idx = base + i;
        if (idx < N_NODES) rowptr[idx] += off;
    }
    if (blockIdx.x == 0 && t == 0) rowptr[N_NODES] = N_EDGES;
}

// ---------------- Two-phase CSR fill, LDS-ordered ----------------
// Measured lessons:
//  (1) gfx950 L2 does NOT merge temporally-scattered 8 B stores — every
//      global-scatter scheme paid ~6x write-back amplification. Scatter in
//      LDS, write out coalesced.
//  (2) gfx950 global atomics scattered over a small array are also ~64 B
//      write-back each. Count in LDS per subwindow instead (subcount).
//  (3) [R8-R12] Channel-blocked gather layouts (16 ch/row) cut FETCH
//      193->88 MB but halve line utilization and double distinct lines per
//      wave instruction -> 1.2 TB/s vs 3.6 TB/s effective; all four
//      variants lost to the full-row gather below. Row gathers must be
//      wave-coherent full rows.

__global__ __launch_bounds__(256) void binA_kernel(
        const int* __restrict__ src, const int* __restrict__ dst,
        int* __restrict__ cursor, int2* __restrict__ staging) {
    __shared__ int2 buf[ACHUNK];                 // 32 KB
    __shared__ int cnt_s[SUBW], off_s[SUBW], cur_s[SUBW], gb_s[SUBW], sh[SUBW];
    int t = threadIdx.x;
    cnt_s[t] = 0;
    __syncthreads();

    int base = blockIdx.x * ACHUNK;
    int n = N_EDGES - base;
    if (n > ACHUNK) n = ACHUNK;

    // pass 1: count bins
    for (int li = t; li < n; li += 256)
        atomicAdd(&cnt_s[dst[base + li] / SUBW_NODES], 1);
    __syncthreads();

    // exclusive scan over 256 bins
    int v = cnt_s[t];
    sh[t] = v;
    __syncthreads();
    for (int off = 1; off < SUBW; off <<= 1) {
        int y = (t >= off) ? sh[t - off] : 0;
        __syncthreads();
        sh[t] += y;
        __syncthreads();
    }
    int excl = sh[t] - v;
    off_s[t] = excl;
    cur_s[t] = excl;
    gb_s[t] = atomicAdd(&cursor[t], v);
    __syncthreads();

    // pass 2: re-read (L2-hot) and scatter into LDS bin-contiguous buffer
    for (int li = t; li < n; li += 256) {
        int e = base + li;
        int d = dst[e], s = src[e];
        int p = atomicAdd(&cur_s[d / SUBW_NODES], 1);
        buf[p] = make_int2(s, d);
    }
    __syncthreads();

    // flush: contiguous ~128 B runs per bin into per-subwindow staging
    for (int i = t; i < n; i += 256) {
        int2 e = buf[i];
        int w = e.y / SUBW_NODES;
        int idx = gb_s[w] + (i - off_s[w]);
        if (idx < SCAP) staging[(size_t)w * SCAP + idx] = e;
    }
}

__global__ __launch_bounds__(256) void subcount_kernel(
        const int2* __restrict__ staging, const int* __restrict__ cursor,
        int* __restrict__ cnt) {
    __shared__ int hist[SUBW_NODES];
    int b = blockIdx.x, t = threadIdx.x;
    int n0 = b * SUBW_NODES;
    int n1 = n0 + SUBW_NODES;
    if (n1 > N_NODES) n1 = N_NODES;
    int nn = n1 - n0;
    for (int i = t; i < nn; i += 256) hist[i] = 0;
    __syncthreads();
    int m = cursor[b];
    if (m > SCAP) m = SCAP;
    for (int i = t; i < m; i += 256) {
        int d = staging[(size_t)b * SCAP + i].y;
        atomicAdd(&hist[d - n0], 1);
    }
    __syncthreads();
    for (int i = t; i < nn; i += 256) cnt[n0 + i] = hist[i];
}

__global__ __launch_bounds__(512) void binB_kernel(
        const int2* __restrict__ staging, const int* __restrict__ cursor,
        const int* __restrict__ rowptr, const float* __restrict__ dinv,
        int2* __restrict__ edges) {
    __shared__ int rowl[SUBW_NODES + 1];
    __shared__ int lcur[SUBW_NODES];
    __shared__ int2 ebuf[EBUF];                  // 64 KB
    int b = blockIdx.x, t = threadIdx.x;
    int n0 = b * SUBW_NODES;
    int n1 = n0 + SUBW_NODES;
    if (n1 > N_NODES) n1 = N_NODES;
    int nn = n1 - n0;

    for (int i = t; i <= nn; i += 512) rowl[i] = rowptr[n0 + i];
    for (int i = t; i < nn; i += 512) lcur[i] = 0;
    __syncthreads();

    int gb = rowl[0];
    int total = rowl[nn] - gb;
    int m = cursor[b];
    if (m > SCAP) m = SCAP;

    for (int i = t; i < m; i += 512) {
        int2 e = staging[(size_t)b * SCAP + i];
        int s = e.x, d = e.y;
        float wt = dinv[s] * dinv[d];
        int dl = d - n0;
        int lpos = (rowl[dl] - gb) + atomicAdd(&lcur[dl], 1);
        if (lpos < EBUF) ebuf[lpos] = make_int2(s, __float_as_int(wt));
    }
    __syncthreads();

    // fully coalesced ordered write-out of this subwindow's CSR range
    for (int i = t; i < total; i += 512)
        if (i < EBUF) edges[gb + i] = ebuf[i];
}

// ---------------- W pre-pack: conv_w[L][k][n] -> W2g[L][n][132 dwords] ----------------

__global__ void wpack_kernel(const float* __restrict__ conv_w, unsigned int* __restrict__ W2g) {
    int idx = blockIdx.x * 256 + threadIdx.x;
    if (idx < N_CONVS * 16384) {
        int L = idx >> 14;
        int e = idx & 16383;
        int k = e >> 7;
        int n = e & 127;
        float f = conv_w[(size_t)L * 16384 + k * 128 + n];
        W2g[(size_t)L * W2_LAYER + n * W2_STRIDE + k] = pack_hilo(f);
    }
}

// ---------------- MFMA GEMM: H = X @ W via split-bf16, 32 rows/wave, fp16 out ------
// Templated on input dtype: layer 0 reads fp32 x_in; layers 1-3 read fp16 bufA.
// Row-major fp16 throughout (channel-blocked variants measured slower: R8-R12).

template<bool F16IN>
__global__ __launch_bounds__(256, 2) void gemm_mfma_t(const void* __restrict__ Xv,
                                                      const unsigned int* __restrict__ W2g,
                                                      __half* __restrict__ Hh) {
    __shared__ unsigned int wlds[128 * W2_STRIDE];   // 67584 B
    int t = threadIdx.x;

    {   // stage packed W (16896 dwords)
        const uint4* s4 = (const uint4*)W2g;
        uint4* d4 = (uint4*)wlds;
#pragma unroll
        for (int i = 0; i < 17; i++) {
            int idx = i * 256 + t;
            if (idx < (128 * W2_STRIDE) / 4) d4[idx] = s4[idx];
        }
    }
    __syncthreads();

    int w = t >> 6;
    int l = t & 63;
    int m = l & 15;        // A row within tile / B col / C col
    int q = l >> 4;        // quad: k-offset q*8, C row-offset q*4
    int r0 = blockIdx.x * 128 + w * 32 + m;
    int r1 = r0 + 16;
    int r0c = (r0 > N_NODES - 1) ? (N_NODES - 1) : r0;
    int r1c = (r1 > N_NODES - 1) ? (N_NODES - 1) : r1;

    uint4 a0[8], a1[8];
#pragma unroll
    for (int i = 0; i < 8; i++) {
        if constexpr (F16IN) {
            const uint2* X2 = (const uint2*)Xv;   // 32 uint2 (4 halves each) per row
            uint2 hv = X2[(size_t)r0c * 32 + i * 4 + q];
            float2 f0 = __half22float2(*(const __half2*)&hv.x);
            float2 f1 = __half22float2(*(const __half2*)&hv.y);
            a0[i].x = pack_hilo(f0.x); a0[i].y = pack_hilo(f0.y);
            a0[i].z = pack_hilo(f1.x); a0[i].w = pack_hilo(f1.y);
            uint2 gv = X2[(size_t)r1c * 32 + i * 4 + q];
            float2 g0 = __half22float2(*(const __half2*)&gv.x);
            float2 g1 = __half22float2(*(const __half2*)&gv.y);
            a1[i].x = pack_hilo(g0.x); a1[i].y = pack_hilo(g0.y);
            a1[i].z = pack_hilo(g1.x); a1[i].w = pack_hilo(g1.y);
        } else {
            const float4* X4 = (const float4*)Xv;
            float4 xv = X4[(size_t)r0c * 32 + i * 4 + q];
            a0[i].x = pack_hilo(xv.x); a0[i].y = pack_hilo(xv.y);
            a0[i].z = pack_hilo(xv.z); a0[i].w = pack_hilo(xv.w);
            float4 yv = X4[(size_t)r1c * 32 + i * 4 + q];
            a1[i].x = pack_hilo(yv.x); a1[i].y = pack_hilo(yv.y);
            a1[i].z = pack_hilo(yv.z); a1[i].w = pack_hilo(yv.w);
        }
    }

    f32x4 acc0[8], acc1[8];
#pragma unroll
    for (int nb = 0; nb < 8; nb++) {
        acc0[nb] = (f32x4){0.f, 0.f, 0.f, 0.f};
        acc1[nb] = (f32x4){0.f, 0.f, 0.f, 0.f};
    }

#pragma unroll
    for (int nb = 0; nb < 8; nb++) {
        const unsigned int* wb = &wlds[(nb * 16 + m) * W2_STRIDE];
#pragma unroll
        for (int i = 0; i < 8; i++) {
            uint4 b = *(const uint4*)(wb + i * 16 + q * 4);
            FragU fa0, fa1, fb, fr;
            fa0.u = a0[i]; fa1.u = a1[i]; fb.u = b;
            acc0[nb] = __builtin_amdgcn_mfma_f32_16x16x32_bf16(fa0.v, fb.v, acc0[nb], 0, 0, 0);
            acc1[nb] = __builtin_amdgcn_mfma_f32_16x16x32_bf16(fa1.v, fb.v, acc1[nb], 0, 0, 0);
            fr.u.x = (b.x >> 16) | (b.x << 16);
            fr.u.y = (b.y >> 16) | (b.y << 16);
            fr.u.z = (b.z >> 16) | (b.z << 16);
            fr.u.w = (b.w >> 16) | (b.w << 16);
            acc0[nb] = __builtin_amdgcn_mfma_f32_16x16x32_bf16(fa0.v, fr.v, acc0[nb], 0, 0, 0);
            acc1[nb] = __builtin_amdgcn_mfma_f32_16x16x32_bf16(fa1.v, fr.v, acc1[nb], 0, 0, 0);
        }
    }

    // C/D: col = m, row = q*4 + r within tile
    int rbase = blockIdx.x * 128 + w * 32 + q * 4;
#pragma unroll
    for (int nb = 0; nb < 8; nb++) {
#pragma unroll
        for (int r = 0; r < 4; r++) {
            int row = rbase + r;
            if (row < N_NODES) Hh[(size_t)row * F + nb * 16 + m] = __float2half(acc0[nb][r]);
            int row1 = row + 16;
            if (row1 < N_NODES) Hh[(size_t)row1 * F + nb * 16 + m] = __float2half(acc1[nb][r]);
        }
    }
}

// ---------------- Aggregation: x_out = relu(agg + 2*dinv^2*h + b), fp16 in/out ----
// One wave per node; lane = (slot = lane>>4, c16 = lane&15); uint4 gathers.
// Each gathered H-row (256 B) is read by 16 lanes as full contiguous 256 B
// -> 4 coherent rows per wave instruction, 100% line utilization, measured
// 3.6 TB/s effective (the LLC->L2 path ceiling; 193 MB FETCH is the 8-XCD
// compulsory floor: private L2s each touch ~all of H). 62 us/layer ~ 1.15x
// the 54 us path floor. Channel-blocked alternatives measured worse (R8-R12).

__global__ __launch_bounds__(256) void agg_kernel(const uint4* __restrict__ H16,
                                                  const int* __restrict__ rowptr,
                                                  const int2* __restrict__ edges,
                                                  const float* __restrict__ dinv,
                                                  const float4* __restrict__ bias4,
                                                  uint4* __restrict__ Xo) {
    int node = blockIdx.x * 4 + (threadIdx.x >> 6);
    if (node >= N_NODES) return;
    int lane = threadIdx.x & 63;
    int c16 = lane & 15;
    int slot = lane >> 4;

    int lo = rowptr[node];
    int hi = rowptr[node + 1];
    int him1 = hi - 1;

    float4 aL = make_float4(0.f, 0.f, 0.f, 0.f);
    float4 aH = make_float4(0.f, 0.f, 0.f, 0.f);

    for (int i = lo + slot; i < hi; i += 16) {
        int s[4]; float w[4]; uint4 v[4];
#pragma unroll
        for (int j = 0; j < 4; j++) {
            int ij = i + 4 * j;
            int cj = (ij < him1) ? ij : him1;
            int2 e = edges[cj];
            s[j] = e.x;
            w[j] = (ij < hi) ? __int_as_float(e.y) : 0.f;
        }
#pragma unroll
        for (int j = 0; j < 4; j++) v[j] = H16[(size_t)s[j] * 16 + c16];
#pragma unroll
        for (int j = 0; j < 4; j++) {
            HU4 x; x.u = v[j];
            float2 p0 = __half22float2(x.h[0]);
            float2 p1 = __half22float2(x.h[1]);
            float2 p2 = __half22float2(x.h[2]);
            float2 p3 = __half22float2(x.h[3]);
            aL.x = fmaf(w[j], p0.x, aL.x); aL.y = fmaf(w[j], p0.y, aL.y);
            aL.z = fmaf(w[j], p1.x, aL.z); aL.w = fmaf(w[j], p1.y, aL.w);
            aH.x = fmaf(w[j], p2.x, aH.x); aH.y = fmaf(w[j], p2.y, aH.y);
            aH.z = fmaf(w[j], p3.x, aH.z); aH.w = fmaf(w[j], p3.y, aH.w);
        }
    }

    aL.x += __shfl_down(aL.x, 32, 64); aL.y += __shfl_down(aL.y, 32, 64);
    aL.z += __shfl_down(aL.z, 32, 64); aL.w += __shfl_down(aL.w, 32, 64);
    aH.x += __shfl_down(aH.x, 32, 64); aH.y += __shfl_down(aH.y, 32, 64);
    aH.z += __shfl_down(aH.z, 32, 64); aH.w += __shfl_down(aH.w, 32, 64);
    aL.x += __shfl_down(aL.x, 16, 64); aL.y += __shfl_down(aL.y, 16, 64);
    aL.z += __shfl_down(aL.z, 16, 64); aL.w += __shfl_down(aL.w, 16, 64);
    aH.x += __shfl_down(aH.x, 16, 64); aH.y += __shfl_down(aH.y, 16, 64);
    aH.z += __shfl_down(aH.z, 16, 64); aH.w += __shfl_down(aH.w, 16, 64);

    if (slot == 0) {
        float dn = dinv[node];
        float sw = 2.0f * dn * dn;
        HU4 x; x.u = H16[(size_t)node * 16 + c16];
        float2 p0 = __half22float2(x.h[0]);
        float2 p1 = __half22float2(x.h[1]);
        float2 p2 = __half22float2(x.h[2]);
        float2 p3 = __half22float2(x.h[3]);
        float4 bL = bias4[c16 * 2];
        float4 bH = bias4[c16 * 2 + 1];
        float4 rL, rH;
        rL.x = fmaxf(fmaf(sw, p0.x, aL.x) + bL.x, 0.f);
        rL.y = fmaxf(fmaf(sw, p0.y, aL.y) + bL.y, 0.f);
        rL.z = fmaxf(fmaf(sw, p1.x, aL.z) + bL.z, 0.f);
        rL.w = fmaxf(fmaf(sw, p1.y, aL.w) + bL.w, 0.f);
        rH.x = fmaxf(fmaf(sw, p2.x, aH.x) + bH.x, 0.f);
        rH.y = fmaxf(fmaf(sw, p2.y, aH.y) + bH.y, 0.f);
        rH.z = fmaxf(fmaf(sw, p3.x, aH.z) + bH.z, 0.f);
        rH.w = fmaxf(fmaf(sw, p3.y, aH.w) + bH.w, 0.f);
        HU4 o;
        o.h[0] = __floats2half2_rn(rL.x, rL.y);
        o.h[1] = __floats2half2_rn(rL.z, rL.w);
        o.h[2] = __floats2half2_rn(rH.x, rH.y);
        o.h[3] = __floats2half2_rn(rH.z, rH.w);
        Xo[(size_t)node * 16 + c16] = o.u;
    }
}

// ---------------- Fused mean-pool + FC1(relu) + FC2 (fp16 x) ----------------

__global__ __launch_bounds__(256) void pool_fc_kernel(const __half* __restrict__ x,
                                                      const int* __restrict__ batch,
                                                      const float* __restrict__ fc1w,
                                                      const float* __restrict__ fc1b,
                                                      const float* __restrict__ fc2w,
                                                      const float* __restrict__ fc2b,
                                                      float* __restrict__ out) {
    __shared__ float part[2][F];
    __shared__ float pooled[F];
    __shared__ int bnd[2];
    __shared__ float red[2];
    int g = blockIdx.x, t = threadIdx.x;
    int c = t & 127, hlf = t >> 7;

    if (t < 2) {
        int target = g + t;
        int lo = 0, hi = N_NODES;
        while (lo < hi) {
            int m = (lo + hi) >> 1;
            if (batch[m] < target) lo = m + 1;
            else hi = m;
        }
        bnd[t] = lo;
    }
    __syncthreads();
    int lo = bnd[0], hi = bnd[1];

    float s = 0.f;
    int n = lo + hlf;
    for (; n + 6 < hi; n += 8) {
        float v0 = __half2float(x[(size_t)n * F + c]);
        float v1 = __half2float(x[(size_t)(n + 2) * F + c]);
        float v2 = __half2float(x[(size_t)(n + 4) * F + c]);
        float v3 = __half2float(x[(size_t)(n + 6) * F + c]);
        s += (v0 + v1) + (v2 + v3);
    }
    for (; n < hi; n += 2) s += __half2float(x[(size_t)n * F + c]);
    part[hlf][c] = s;
    __syncthreads();

    if (t < F) {
        float cntf = fmaxf((float)(hi - lo), 1.0f);
        pooled[c] = (part[0][c] + part[1][c]) / cntf;
    }
    __syncthreads();

    if (t < F) {
        float acc = fc1b[t];
#pragma unroll 4
        for (int k = 0; k < F; k++) acc = fmaf(pooled[k], fc1w[k * F + t], acc);
        acc = fmaxf(acc, 0.f);

        float p = acc * fc2w[t];
#pragma unroll
        for (int o = 32; o > 0; o >>= 1) p += __shfl_down(p, o, 64);
        if ((t & 63) == 0) red[t >> 6] = p;
    }
    __syncthreads();
    if (t == 0) out[g] = red[0] + red[1] + fc2b[0];
}

// ---------------- launch ----------------

extern "C" void kernel_launch(void* const* d_in, const int* in_sizes, int n_in,
                              void* d_out, int out_size, void* d_ws, size_t ws_size,
                              hipStream_t stream) {
    const float* x_in   = (const float*)d_in[0];
    const int*   eidx   = (const int*)d_in[1];
    const int*   batch  = (const int*)d_in[2];
    const float* conv_w = (const float*)d_in[4];
    const float* conv_b = (const float*)d_in[5];
    const float* fc1w   = (const float*)d_in[6];
    const float* fc1b   = (const float*)d_in[7];
    const float* fc2w   = (const float*)d_in[8];
    const float* fc2b   = (const float*)d_in[9];
    float* out = (float*)d_out;

    const int* src = eidx;
    const int* dst = eidx + N_EDGES;

    char* ws = (char*)d_ws;
    size_t off = 0;
    auto alloc = [&](size_t bytes) -> char* {
        char* p = ws + off;
        off += (bytes + 255) & ~(size_t)255;
        return p;
    };
    __half* bufA  = (__half*)alloc((size_t)N_NODES * F * 2);   // 25.6 MB fp16 (agg out)
    __half* bufH  = (__half*)alloc((size_t)N_NODES * F * 2);   // 25.6 MB fp16 (gemm out)
    float*  dinv  = (float*)alloc((size_t)N_NODES * 4);
    int*    cnt   = (int*)alloc((size_t)N_NODES * 4);
    int*    rowp  = (int*)alloc((size_t)(N_NODES + 1) * 4);
    int2*   edges = (int2*)alloc((size_t)N_EDGES * 8);         // 12.8 MB packed
    unsigned int* W2g = (unsigned int*)alloc((size_t)N_CONVS * W2_LAYER * 4);  // 264 KB
    int*    blks  = (int*)alloc(128 * 4);
    int*    cursor = (int*)alloc(SUBW * 4);
    int2*   staging = (int2*)alloc((size_t)SUBW * SCAP * 8);   // 14.4 MB
    (void)ws_size; (void)in_sizes; (void)n_in; (void)out_size;

    // --- bucket edges first (needs no counts), then LDS-histogram counting ---
    hipMemsetAsync(cursor, 0, SUBW * 4, stream);
    binA_kernel<<<BINA_BLOCKS, 256, 0, stream>>>(src, dst, cursor, staging);
    subcount_kernel<<<SUBW, 256, 0, stream>>>(staging, cursor, cnt);

    // --- CSR prep + W pre-pack ---
    dinv_kernel<<<(N_NODES + 255) / 256, 256, 0, stream>>>(cnt, dinv);
    scan1_kernel<<<SCAN_NBLK, 256, 0, stream>>>(cnt, rowp, blks);
    scan2_kernel<<<1, 128, 0, stream>>>(blks, SCAN_NBLK);
    scan3_kernel<<<SCAN_NBLK, 256, 0, stream>>>(rowp, blks);
    wpack_kernel<<<(N_CONVS * 16384 + 255) / 256, 256, 0, stream>>>(conv_w, W2g);

    // --- LDS-ordered coalesced CSR fill ---
    binB_kernel<<<SUBW, 512, 0, stream>>>(staging, cursor, rowp, dinv, edges);

    // --- 4 GCN layers: MFMA GEMM (fp16 out) + gather agg (fp16 out) ---
    for (int L = 0; L < N_CONVS; L++) {
        if (L == 0)
            gemm_mfma_t<false><<<(N_NODES + 127) / 128, 256, 0, stream>>>(
                (const void*)x_in, W2g, bufH);
        else
            gemm_mfma_t<true><<<(N_NODES + 127) / 128, 256, 0, stream>>>(
                (const void*)bufA, W2g + (size_t)L * W2_LAYER, bufH);
        agg_kernel<<<(N_NODES + 3) / 4, 256, 0, stream>>>(
            (const uint4*)bufH, rowp, edges, dinv,
            (const float4*)(conv_b + (size_t)L * F), (uint4*)bufA);
    }

    // --- mean-pool + FC head ---
    pool_fc_kernel<<<N_GRAPHS, 256, 0, stream>>>(bufA, batch, fc1w, fc1b, fc2w, fc2b, out);
}

// Round 14
// 510.288 us; speedup vs baseline: 2.8356x; 1.0170x over previous
//
#include <hip/hip_runtime.h>
#include <hip/hip_fp16.h>

#define N_NODES 100000
#define N_EDGES 1600000
#define N_GRAPHS 512
#define F 128
#define N_CONVS 4
#define SCAN_NBLK ((N_NODES + 1023) / 1024)   // 98

// two-phase fill, 256 subwindows so phase-B scatter fits in LDS
#define SUBW 256
#define SUBW_NODES 391                         // ceil(100000/256)
#define SCAP 7040                              // per-subwindow staging cap (mean 6256 + 10 sigma)
#define ACHUNK 4096
#define BINA_BLOCKS ((N_EDGES + ACHUNK - 1) / ACHUNK)  // 391
#define EBUF 8192                              // LDS edge buffer (mean 6256 + 24 sigma)

// 2-way channel-split aggregation: 2 blocks of 64 ch; 8 nodes per 256-thr block
#define AGG64_BLOCKS ((N_NODES / 8) * 2)       // 25000

// packed W2 row stride: 256 bf16 (hi/lo interleaved) padded to 264 = 132 dwords
#define W2_STRIDE 132
#define W2_LAYER (128 * W2_STRIDE)            // dwords per layer

typedef __attribute__((ext_vector_type(8))) short short8;   // 8 bf16 (4 VGPRs)
typedef __attribute__((ext_vector_type(4))) float f32x4;

union FragU { uint4 u; short8 v; };
union HU4 { uint4 u; __half2 h[4]; };

// split f into truncated-bf16 hi/lo, packed (hi in low16, lo in high16).
__device__ __forceinline__ unsigned int pack_hilo(float f) {
    unsigned int u = __float_as_uint(f);
    unsigned int hb = u & 0xFFFF0000u;
    float d = f - __uint_as_float(hb);
    unsigned int lb = __float_as_uint(d) >> 16;
    return (u >> 16) | (lb << 16);
}

// ---------------- CSR build ----------------

__global__ void dinv_kernel(const int* __restrict__ cnt, float* __restrict__ dinv) {
    int n = blockIdx.x * blockDim.x + threadIdx.x;
    if (n < N_NODES) dinv[n] = rsqrtf((float)cnt[n] + 2.0f);  // improved=True
}

__global__ void scan1_kernel(const int* __restrict__ cnt, int* __restrict__ excl,
                             int* __restrict__ blksum) {
    __shared__ int sums[256];
    int t = threadIdx.x;
    int base = blockIdx.x * 1024 + t * 4;
    int v0 = 0, v1 = 0, v2 = 0, v3 = 0;
    if (base + 0 < N_NODES) v0 = cnt[base + 0];
    if (base + 1 < N_NODES) v1 = cnt[base + 1];
    if (base + 2 < N_NODES) v2 = cnt[base + 2];
    if (base + 3 < N_NODES) v3 = cnt[base + 3];
    int s = v0 + v1 + v2 + v3;
    sums[t] = s;
    __syncthreads();
    for (int off = 1; off < 256; off <<= 1) {
        int y = (t >= off) ? sums[t - off] : 0;
        __syncthreads();
        sums[t] += y;
        __syncthreads();
    }
    int pre = sums[t] - s;
    if (base + 0 < N_NODES) excl[base + 0] = pre;
    if (base + 1 < N_NODES) excl[base + 1] = pre + v0;
    if (base + 2 < N_NODES) excl[base + 2] = pre + v0 + v1;
    if (base + 3 < N_NODES) excl[base + 3] = pre + v0 + v1 + v2;
    if (t == 255) blksum[blockIdx.x] = sums[255];
}

__global__ void scan2_kernel(int* __restrict__ blksum, int nblk) {
    __shared__ int sh[128];
    int t = threadIdx.x;
    int v = (t < nblk) ? blksum[t] : 0;
    sh[t] = v;
    __syncthreads();
    for (int off = 1; off < 128; off <<= 1) {
        int y = (t >= off) ? sh[t - off] : 0;
        __syncthreads();
        sh[t] += y;
        __syncthreads();
    }
    if (t < nblk) blksum[t] = sh[t] - v;
}

__global__ void scan3_kernel(int* __restrict__ rowptr, const int* __restrict__ blksum) {
    int t = threadIdx.x;
    int base = blockIdx.x * 1024 + t * 4;
    int off = blksum[blockIdx.x];
#pragma unroll
    for (int i = 0; i < 4; i++) {
        int idx = base + i;
        if (idx < N_NODES) rowptr[idx] += off;
    }
    if (blockIdx.x == 0 && t == 0) rowptr[N_NODES] = N_EDGES;
}

// ---------------- Two-phase CSR fill, LDS-ordered ----------------
// Measured lessons:
//  (1) gfx950 L2 does NOT merge temporally-scattered 8 B stores — scatter in
//      LDS, write out coalesced.
//  (2) Scattered global atomics pay ~64 B write-back each. Count in LDS.
//  (3) [R8-R12] 16-ch gather rows (32 B) double distinct lines per wave
//      instruction and halve line utilization -> 1.2 TB/s. Gather rows must
//      be whole cache lines with ~16 distinct lines per instruction.

__global__ __launch_bounds__(256) void binA_kernel(
        const int* __restrict__ src, const int* __restrict__ dst,
        int* __restrict__ cursor, int2* __restrict__ staging) {
    __shared__ int2 buf[ACHUNK];                 // 32 KB
    __shared__ int cnt_s[SUBW], off_s[SUBW], cur_s[SUBW], gb_s[SUBW], sh[SUBW];
    int t = threadIdx.x;
    cnt_s[t] = 0;
    __syncthreads();

    int base = blockIdx.x * ACHUNK;
    int n = N_EDGES - base;
    if (n > ACHUNK) n = ACHUNK;

    // pass 1: count bins
    for (int li = t; li < n; li += 256)
        atomicAdd(&cnt_s[dst[base + li] / SUBW_NODES], 1);
    __syncthreads();

    // exclusive scan over 256 bins
    int v = cnt_s[t];
    sh[t] = v;
    __syncthreads();
    for (int off = 1; off < SUBW; off <<= 1) {
        int y = (t >= off) ? sh[t - off] : 0;
        __syncthreads();
        sh[t] += y;
        __syncthreads();
    }
    int excl = sh[t] - v;
    off_s[t] = excl;
    cur_s[t] = excl;
    gb_s[t] = atomicAdd(&cursor[t], v);
    __syncthreads();

    // pass 2: re-read (L2-hot) and scatter into LDS bin-contiguous buffer
    for (int li = t; li < n; li += 256) {
        int e = base + li;
        int d = dst[e], s = src[e];
        int p = atomicAdd(&cur_s[d / SUBW_NODES], 1);
        buf[p] = make_int2(s, d);
    }
    __syncthreads();

    // flush: contiguous ~128 B runs per bin into per-subwindow staging
    for (int i = t; i < n; i += 256) {
        int2 e = buf[i];
        int w = e.y / SUBW_NODES;
        int idx = gb_s[w] + (i - off_s[w]);
        if (idx < SCAP) staging[(size_t)w * SCAP + idx] = e;
    }
}

__global__ __launch_bounds__(256) void subcount_kernel(
        const int2* __restrict__ staging, const int* __restrict__ cursor,
        int* __restrict__ cnt) {
    __shared__ int hist[SUBW_NODES];
    int b = blockIdx.x, t = threadIdx.x;
    int n0 = b * SUBW_NODES;
    int n1 = n0 + SUBW_NODES;
    if (n1 > N_NODES) n1 = N_NODES;
    int nn = n1 - n0;
    for (int i = t; i < nn; i += 256) hist[i] = 0;
    __syncthreads();
    int m = cursor[b];
    if (m > SCAP) m = SCAP;
    for (int i = t; i < m; i += 256) {
        int d = staging[(size_t)b * SCAP + i].y;
        atomicAdd(&hist[d - n0], 1);
    }
    __syncthreads();
    for (int i = t; i < nn; i += 256) cnt[n0 + i] = hist[i];
}

__global__ __launch_bounds__(512) void binB_kernel(
        const int2* __restrict__ staging, const int* __restrict__ cursor,
        const int* __restrict__ rowptr, const float* __restrict__ dinv,
        int2* __restrict__ edges) {
    __shared__ int rowl[SUBW_NODES + 1];
    __shared__ int lcur[SUBW_NODES];
    __shared__ int2 ebuf[EBUF];                  // 64 KB
    int b = blockIdx.x, t = threadIdx.x;
    int n0 = b * SUBW_NODES;
    int n1 = n0 + SUBW_NODES;
    if (n1 > N_NODES) n1 = N_NODES;
    int nn = n1 - n0;

    for (int i = t; i <= nn; i += 512) rowl[i] = rowptr[n0 + i];
    for (int i = t; i < nn; i += 512) lcur[i] = 0;
    __syncthreads();

    int gb = rowl[0];
    int total = rowl[nn] - gb;
    int m = cursor[b];
    if (m > SCAP) m = SCAP;

    for (int i = t; i < m; i += 512) {
        int2 e = staging[(size_t)b * SCAP + i];
        int s = e.x, d = e.y;
        float wt = dinv[s] * dinv[d];
        int dl = d - n0;
        int lpos = (rowl[dl] - gb) + atomicAdd(&lcur[dl], 1);
        if (lpos < EBUF) ebuf[lpos] = make_int2(s, __float_as_int(wt));
    }
    __syncthreads();

    // fully coalesced ordered write-out of this subwindow's CSR range
    for (int i = t; i < total; i += 512)
        if (i < EBUF) edges[gb + i] = ebuf[i];
}

// ---------------- W pre-pack: conv_w[L][k][n] -> W2g[L][n][132 dwords] ----------------

__global__ void wpack_kernel(const float* __restrict__ conv_w, unsigned int* __restrict__ W2g) {
    int idx = blockIdx.x * 256 + threadIdx.x;
    if (idx < N_CONVS * 16384) {
        int L = idx >> 14;
        int e = idx & 16383;
        int k = e >> 7;
        int n = e & 127;
        float f = conv_w[(size_t)L * 16384 + k * 128 + n];
        W2g[(size_t)L * W2_LAYER + n * W2_STRIDE + k] = pack_hilo(f);
    }
}

// ---------------- MFMA GEMM: H = X @ W via split-bf16, 32 rows/wave, fp16 out ------
// Node features now use the 2-BLOCK channel layout:
//   buf[((c>>6)*N_NODES + node)*64 + (c&63)]   (two 128 B half-rows per node)
// so each XCD's aggregation gather touches only a 12.8 MB half of H (the
// byte-vs-request discriminating experiment; see agg64 comment).

template<bool F16IN>
__global__ __launch_bounds__(256, 2) void gemm_mfma_t(const void* __restrict__ Xv,
                                                      const unsigned int* __restrict__ W2g,
                                                      __half* __restrict__ Hh) {
    __shared__ unsigned int wlds[128 * W2_STRIDE];   // 67584 B
    int t = threadIdx.x;

    {   // stage packed W (16896 dwords)
        const uint4* s4 = (const uint4*)W2g;
        uint4* d4 = (uint4*)wlds;
#pragma unroll
        for (int i = 0; i < 17; i++) {
            int idx = i * 256 + t;
            if (idx < (128 * W2_STRIDE) / 4) d4[idx] = s4[idx];
        }
    }
    __syncthreads();

    int w = t >> 6;
    int l = t & 63;
    int m = l & 15;        // A row within tile / B col / C col
    int q = l >> 4;        // quad: k-offset q*8, C row-offset q*4
    int r0 = blockIdx.x * 128 + w * 32 + m;
    int r1 = r0 + 16;
    int r0c = (r0 > N_NODES - 1) ? (N_NODES - 1) : r0;
    int r1c = (r1 > N_NODES - 1) ? (N_NODES - 1) : r1;

    uint4 a0[8], a1[8];
#pragma unroll
    for (int i = 0; i < 8; i++) {
        if constexpr (F16IN) {
            // channels 16i+4q..+3 = block i>>2, local (i&3)*16+4q; uint2 = 4 halves
            const uint2* X2 = (const uint2*)Xv;
            uint2 hv = X2[((size_t)(i >> 2) * N_NODES + r0c) * 16 + (i & 3) * 4 + q];
            float2 f0 = __half22float2(*(const __half2*)&hv.x);
            float2 f1 = __half22float2(*(const __half2*)&hv.y);
            a0[i].x = pack_hilo(f0.x); a0[i].y = pack_hilo(f0.y);
            a0[i].z = pack_hilo(f1.x); a0[i].w = pack_hilo(f1.y);
            uint2 gv = X2[((size_t)(i >> 2) * N_NODES + r1c) * 16 + (i & 3) * 4 + q];
            float2 g0 = __half22float2(*(const __half2*)&gv.x);
            float2 g1 = __half22float2(*(const __half2*)&gv.y);
            a1[i].x = pack_hilo(g0.x); a1[i].y = pack_hilo(g0.y);
            a1[i].z = pack_hilo(g1.x); a1[i].w = pack_hilo(g1.y);
        } else {
            const float4* X4 = (const float4*)Xv;  // fp32 row-major input (layer 0)
            float4 xv = X4[(size_t)r0c * 32 + i * 4 + q];
            a0[i].x = pack_hilo(xv.x); a0[i].y = pack_hilo(xv.y);
            a0[i].z = pack_hilo(xv.z); a0[i].w = pack_hilo(xv.w);
            float4 yv = X4[(size_t)r1c * 32 + i * 4 + q];
            a1[i].x = pack_hilo(yv.x); a1[i].y = pack_hilo(yv.y);
            a1[i].z = pack_hilo(yv.z); a1[i].w = pack_hilo(yv.w);
        }
    }

    f32x4 acc0[8], acc1[8];
#pragma unroll
    for (int nb = 0; nb < 8; nb++) {
        acc0[nb] = (f32x4){0.f, 0.f, 0.f, 0.f};
        acc1[nb] = (f32x4){0.f, 0.f, 0.f, 0.f};
    }

#pragma unroll
    for (int nb = 0; nb < 8; nb++) {
        const unsigned int* wb = &wlds[(nb * 16 + m) * W2_STRIDE];
#pragma unroll
        for (int i = 0; i < 8; i++) {
            uint4 b = *(const uint4*)(wb + i * 16 + q * 4);
            FragU fa0, fa1, fb, fr;
            fa0.u = a0[i]; fa1.u = a1[i]; fb.u = b;
            acc0[nb] = __builtin_amdgcn_mfma_f32_16x16x32_bf16(fa0.v, fb.v, acc0[nb], 0, 0, 0);
            acc1[nb] = __builtin_amdgcn_mfma_f32_16x16x32_bf16(fa1.v, fb.v, acc1[nb], 0, 0, 0);
            fr.u.x = (b.x >> 16) | (b.x << 16);
            fr.u.y = (b.y >> 16) | (b.y << 16);
            fr.u.z = (b.z >> 16) | (b.z << 16);
            fr.u.w = (b.w >> 16) | (b.w << 16);
            acc0[nb] = __builtin_amdgcn_mfma_f32_16x16x32_bf16(fa0.v, fr.v, acc0[nb], 0, 0, 0);
            acc1[nb] = __builtin_amdgcn_mfma_f32_16x16x32_bf16(fa1.v, fr.v, acc1[nb], 0, 0, 0);
        }
    }

    // C/D: col = m, row = q*4 + r; channel nb*16+m -> block nb>>2, local (nb&3)*16+m
    int rbase = blockIdx.x * 128 + w * 32 + q * 4;
#pragma unroll
    for (int nb = 0; nb < 8; nb++) {
#pragma unroll
        for (int r = 0; r < 4; r++) {
            int row = rbase + r;
            if (row < N_NODES)
                Hh[((size_t)(nb >> 2) * N_NODES + row) * 64 + (nb & 3) * 16 + m]
                    = __float2half(acc0[nb][r]);
            int row1 = row + 16;
            if (row1 < N_NODES)
                Hh[((size_t)(nb >> 2) * N_NODES + row1) * 64 + (nb & 3) * 16 + m]
                    = __float2half(acc1[nb][r]);
        }
    }
}

// ---------------- 2-way channel-split aggregation (agg64) ----------------
// Discriminating experiment: R7's full-row gather runs at 3.6 TB/s effective
// with 16 distinct lines per wave instruction and 193 MB FETCH (8 XCDs x
// 25.6 MB compulsory, LLC-served). agg64 keeps EVERYTHING request-shaped the
// same — 128 B rows (2 full lines, 100% util), 8 rows/instr = 16 lines,
// 4-slot/4-batch MLP, 2-level reduction — but halves the bytes: cb =
// blockIdx&1 pins XCD k to half-H (12.8 MB), FETCH -> ~130 MB.
// If byte-limited: ~42-50 us/layer. If request-limited: ~62 us (null; revert).

__global__ __launch_bounds__(256) void agg64_kernel(const uint4* __restrict__ Hq,
                                                    const int* __restrict__ rowptr,
                                                    const int2* __restrict__ edges,
                                                    const float* __restrict__ dinv,
                                                    const float4* __restrict__ bias4,
                                                    uint4* __restrict__ Xo) {
    int cb = blockIdx.x & 1;            // XCD k (= blockIdx%8) always sees cb = k&1
    int grp = blockIdx.x >> 1;          // 0..12499 (100000 = 8*12500, no tail)
    int lane = threadIdx.x & 63;
    int wv = threadIdx.x >> 6;
    int nsub = lane >> 5;               // 2 nodes per wave
    int slot = (lane >> 3) & 3;         // 4 edge slots
    int c8 = lane & 7;                  // 8 x uint4 = 128 B half-row
    int node = grp * 8 + wv * 2 + nsub;
    size_t cbase = (size_t)cb * N_NODES;

    int lo = rowptr[node];
    int hi = rowptr[node + 1];
    int him1 = hi - 1;

    float4 aL = make_float4(0.f, 0.f, 0.f, 0.f);
    float4 aH = make_float4(0.f, 0.f, 0.f, 0.f);

    for (int i = lo + slot; i < hi; i += 16) {
        int s[4]; float w[4]; uint4 v[4];
#pragma unroll
        for (int j = 0; j < 4; j++) {
            int ij = i + 4 * j;
            int cj = (ij < him1) ? ij : him1;
            int2 e = edges[cj];
            s[j] = e.x;
            w[j] = (ij < hi) ? __int_as_float(e.y) : 0.f;
        }
#pragma unroll
        for (int j = 0; j < 4; j++) v[j] = Hq[(cbase + s[j]) * 8 + c8];
#pragma unroll
        for (int j = 0; j < 4; j++) {
            HU4 x; x.u = v[j];
            float2 p0 = __half22float2(x.h[0]);
            float2 p1 = __half22float2(x.h[1]);
            float2 p2 = __half22float2(x.h[2]);
            float2 p3 = __half22float2(x.h[3]);
            aL.x = fmaf(w[j], p0.x, aL.x); aL.y = fmaf(w[j], p0.y, aL.y);
            aL.z = fmaf(w[j], p1.x, aL.z); aL.w = fmaf(w[j], p1.y, aL.w);
            aH.x = fmaf(w[j], p2.x, aH.x); aH.y = fmaf(w[j], p2.y, aH.y);
            aH.z = fmaf(w[j], p3.x, aH.z); aH.w = fmaf(w[j], p3.y, aH.w);
        }
    }

    // reduce over slot (lane bits 3,4); node bit 5 and c8 bits 0-2 fixed
    aL.x += __shfl_down(aL.x, 16, 64); aL.y += __shfl_down(aL.y, 16, 64);
    aL.z += __shfl_down(aL.z, 16, 64); aL.w += __shfl_down(aL.w, 16, 64);
    aH.x += __shfl_down(aH.x, 16, 64); aH.y += __shfl_down(aH.y, 16, 64);
    aH.z += __shfl_down(aH.z, 16, 64); aH.w += __shfl_down(aH.w, 16, 64);
    aL.x += __shfl_down(aL.x, 8, 64); aL.y += __shfl_down(aL.y, 8, 64);
    aL.z += __shfl_down(aL.z, 8, 64); aL.w += __shfl_down(aL.w, 8, 64);
    aH.x += __shfl_down(aH.x, 8, 64); aH.y += __shfl_down(aH.y, 8, 64);
    aH.z += __shfl_down(aH.z, 8, 64); aH.w += __shfl_down(aH.w, 8, 64);

    if (slot == 0) {
        float dn = dinv[node];
        float sw = 2.0f * dn * dn;
        HU4 x; x.u = Hq[(cbase + node) * 8 + c8];
        float2 p0 = __half22float2(x.h[0]);
        float2 p1 = __half22float2(x.h[1]);
        float2 p2 = __half22float2(x.h[2]);
        float2 p3 = __half22float2(x.h[3]);
        // channels cb*64 + c8*8 + {0..7} -> float4 pairs
        float4 bL = bias4[cb * 16 + c8 * 2];
        float4 bH = bias4[cb * 16 + c8 * 2 + 1];
        float4 rL, rH;
        rL.x = fmaxf(fmaf(sw, p0.x, aL.x) + bL.x, 0.f);
        rL.y = fmaxf(fmaf(sw, p0.y, aL.y) + bL.y, 0.f);
        rL.z = fmaxf(fmaf(sw, p1.x, aL.z) + bL.z, 0.f);
        rL.w = fmaxf(fmaf(sw, p1.y, aL.w) + bL.w, 0.f);
        rH.x = fmaxf(fmaf(sw, p2.x, aH.x) + bH.x, 0.f);
        rH.y = fmaxf(fmaf(sw, p2.y, aH.y) + bH.y, 0.f);
        rH.z = fmaxf(fmaf(sw, p3.x, aH.z) + bH.z, 0.f);
        rH.w = fmaxf(fmaf(sw, p3.y, aH.w) + bH.w, 0.f);
        HU4 o;
        o.h[0] = __floats2half2_rn(rL.x, rL.y);
        o.h[1] = __floats2half2_rn(rL.z, rL.w);
        o.h[2] = __floats2half2_rn(rH.x, rH.y);
        o.h[3] = __floats2half2_rn(rH.z, rH.w);
        Xo[(cbase + node) * 8 + c8] = o.u;
    }
}

// ---------------- Fused mean-pool + FC1(relu) + FC2 (fp16 2-block x) ----------------

__global__ __launch_bounds__(256) void pool_fc_kernel(const __half* __restrict__ x,
                                                      const int* __restrict__ batch,
                                                      const float* __restrict__ fc1w,
                                                      const float* __restrict__ fc1b,
                                                      const float* __restrict__ fc2w,
                                                      const float* __restrict__ fc2b,
                                                      float* __restrict__ out) {
    __shared__ float part[2][F];
    __shared__ float pooled[F];
    __shared__ int bnd[2];
    __shared__ float red[2];
    int g = blockIdx.x, t = threadIdx.x;
    int c = t & 127, hlf = t >> 7;

    if (t < 2) {
        int target = g + t;
        int lo = 0, hi = N_NODES;
        while (lo < hi) {
            int m = (lo + hi) >> 1;
            if (batch[m] < target) lo = m + 1;
            else hi = m;
        }
        bnd[t] = lo;
    }
    __syncthreads();
    int lo = bnd[0], hi = bnd[1];

    // 2-block layout: x[((c>>6)*N + n)*64 + (c&63)]
    size_t cboff = ((size_t)(c >> 6) * N_NODES) * 64 + (c & 63);

    float s = 0.f;
    int n = lo + hlf;
    for (; n + 6 < hi; n += 8) {
        float v0 = __half2float(x[cboff + (size_t)n * 64]);
        float v1 = __half2float(x[cboff + (size_t)(n + 2) * 64]);
        float v2 = __half2float(x[cboff + (size_t)(n + 4) * 64]);
        float v3 = __half2float(x[cboff + (size_t)(n + 6) * 64]);
        s += (v0 + v1) + (v2 + v3);
    }
    for (; n < hi; n += 2) s += __half2float(x[cboff + (size_t)n * 64]);
    part[hlf][c] = s;
    __syncthreads();

    if (t < F) {
        float cntf = fmaxf((float)(hi - lo), 1.0f);
        pooled[c] = (part[0][c] + part[1][c]) / cntf;
    }
    __syncthreads();

    if (t < F) {
        float acc = fc1b[t];
#pragma unroll 4
        for (int k = 0; k < F; k++) acc = fmaf(pooled[k], fc1w[k * F + t], acc);
        acc = fmaxf(acc, 0.f);

        float p = acc * fc2w[t];
#pragma unroll
        for (int o = 32; o > 0; o >>= 1) p += __shfl_down(p, o, 64);
        if ((t & 63) == 0) red[t >> 6] = p;
    }
    __syncthreads();
    if (t == 0) out[g] = red[0] + red[1] + fc2b[0];
}

// ---------------- launch ----------------

extern "C" void kernel_launch(void* const* d_in, const int* in_sizes, int n_in,
                              void* d_out, int out_size, void* d_ws, size_t ws_size,
                              hipStream_t stream) {
    const float* x_in   = (const float*)d_in[0];
    const int*   eidx   = (const int*)d_in[1];
    const int*   batch  = (const int*)d_in[2];
    const float* conv_w = (const float*)d_in[4];
    const float* conv_b = (const float*)d_in[5];
    const float* fc1w   = (const float*)d_in[6];
    const float* fc1b   = (const float*)d_in[7];
    const float* fc2w   = (const float*)d_in[8];
    const float* fc2b   = (const float*)d_in[9];
    float* out = (float*)d_out;

    const int* src = eidx;
    const int* dst = eidx + N_EDGES;

    char* ws = (char*)d_ws;
    size_t off = 0;
    auto alloc = [&](size_t bytes) -> char* {
        char* p = ws + off;
        off += (bytes + 255) & ~(size_t)255;
        return p;
    };
    __half* bufA  = (__half*)alloc((size_t)N_NODES * F * 2);   // 25.6 MB fp16 2-block (agg out)
    __half* bufH  = (__half*)alloc((size_t)N_NODES * F * 2);   // 25.6 MB fp16 2-block (gemm out)
    float*  dinv  = (float*)alloc((size_t)N_NODES * 4);
    int*    cnt   = (int*)alloc((size_t)N_NODES * 4);
    int*    rowp  = (int*)alloc((size_t)(N_NODES + 1) * 4);
    int2*   edges = (int2*)alloc((size_t)N_EDGES * 8);         // 12.8 MB packed
    unsigned int* W2g = (unsigned int*)alloc((size_t)N_CONVS * W2_LAYER * 4);  // 264 KB
    int*    blks  = (int*)alloc(128 * 4);
    int*    cursor = (int*)alloc(SUBW * 4);
    int2*   staging = (int2*)alloc((size_t)SUBW * SCAP * 8);   // 14.4 MB
    (void)ws_size; (void)in_sizes; (void)n_in; (void)out_size;

    // --- bucket edges first (needs no counts), then LDS-histogram counting ---
    hipMemsetAsync(cursor, 0, SUBW * 4, stream);
    binA_kernel<<<BINA_BLOCKS, 256, 0, stream>>>(src, dst, cursor, staging);
    subcount_kernel<<<SUBW, 256, 0, stream>>>(staging, cursor, cnt);

    // --- CSR prep + W pre-pack ---
    dinv_kernel<<<(N_NODES + 255) / 256, 256, 0, stream>>>(cnt, dinv);
    scan1_kernel<<<SCAN_NBLK, 256, 0, stream>>>(cnt, rowp, blks);
    scan2_kernel<<<1, 128, 0, stream>>>(blks, SCAN_NBLK);
    scan3_kernel<<<SCAN_NBLK, 256, 0, stream>>>(rowp, blks);
    wpack_kernel<<<(N_CONVS * 16384 + 255) / 256, 256, 0, stream>>>(conv_w, W2g);

    // --- LDS-ordered coalesced CSR fill ---
    binB_kernel<<<SUBW, 512, 0, stream>>>(staging, cursor, rowp, dinv, edges);

    // --- 4 GCN layers: MFMA GEMM (2-block fp16 out) + 2-way split agg ---
    for (int L = 0; L < N_CONVS; L++) {
        if (L == 0)
            gemm_mfma_t<false><<<(N_NODES + 127) / 128, 256, 0, stream>>>(
                (const void*)x_in, W2g, bufH);
        else
            gemm_mfma_t<true><<<(N_NODES + 127) / 128, 256, 0, stream>>>(
                (const void*)bufA, W2g + (size_t)L * W2_LAYER, bufH);
        agg64_kernel<<<AGG64_BLOCKS, 256, 0, stream>>>(
            (const uint4*)bufH, rowp, edges, dinv,
            (const float4*)(conv_b + (size_t)L * F), (uint4*)bufA);
    }

    // --- mean-pool + FC head ---
    pool_fc_kernel<<<N_GRAPHS, 256, 0, stream>>>(bufA, batch, fc1w, fc1b, fc2w, fc2b, out);
}